// Round 3
// baseline (2136.211 us; speedup 1.0000x reference)
//
#include <hip/hip_runtime.h>
#include <hip/hip_bf16.h>

typedef __attribute__((ext_vector_type(4))) float f32x4;
typedef __attribute__((ext_vector_type(8))) __bf16 bf16x8;
typedef __attribute__((ext_vector_type(8))) unsigned short u16x8;

#define SCALE_ 0.17677669529663687f  /* 32^-0.5 */

// ---------- workspace layout (bytes) ----------
#define OFF_XN 0ull                  // bf16 [100352][384]  (windowed LN1 out; later y2)
#define OFF_AO 77070336ull           // bf16 [100352][384]  (attn out; later g1, y1)
#define OFF_WB 154140672ull          // bf16 weight copies (1,032,192 elems)
#define OFF_WT 156205056ull          // f32 [9][384] repacked dw weights (13824 B)

__device__ __forceinline__ __bf16 tobf(float f) {
  __hip_bfloat16 h = __float2bfloat16(f);
  return __builtin_bit_cast(__bf16, h);
}
__device__ __forceinline__ unsigned short f2u(float f) {
  return __builtin_bit_cast(unsigned short, __float2bfloat16(f));
}

// ---------- fp32 -> bf16 weight copy ----------
__global__ __launch_bounds__(256) void cvt_kernel(const float* __restrict__ src,
                                                  __hip_bfloat16* __restrict__ dst, int n) {
  int i = blockIdx.x * 256 + threadIdx.x;
  int stride = gridDim.x * 256;
  for (; i < n; i += stride) dst[i] = __float2bfloat16(src[i]);
}

// ---------- repack dw weights [384][9] -> [9][384] ----------
__global__ __launch_bounds__(256) void dwrep_kernel(const float* __restrict__ src,
                                                    float* __restrict__ dst) {
  int i = blockIdx.x * 256 + threadIdx.x;
  if (i < 3456) {
    int c = i / 9, k = i - c * 9;
    dst[k * 384 + c] = src[i];
  }
}

// ---------- LayerNorm (one wave per token); WIN: write to rolled+windowed position ----------
template <bool WIN>
__global__ __launch_bounds__(256) void ln_kernel(const float* __restrict__ x,
                                                 const float* __restrict__ gm,
                                                 const float* __restrict__ bt,
                                                 __hip_bfloat16* __restrict__ out) {
  const int tok = blockIdx.x * 4 + (threadIdx.x >> 6);
  const int lane = threadIdx.x & 63;
  const float2* row = (const float2*)(x + (size_t)tok * 384);
  float2 v[3];
  v[0] = row[lane]; v[1] = row[lane + 64]; v[2] = row[lane + 128];
  float s = 0.f, sq = 0.f;
#pragma unroll
  for (int i = 0; i < 3; ++i) { s += v[i].x + v[i].y; sq += v[i].x * v[i].x + v[i].y * v[i].y; }
#pragma unroll
  for (int m = 1; m < 64; m <<= 1) { s += __shfl_xor(s, m, 64); sq += __shfl_xor(sq, m, 64); }
  const float mean = s * (1.f / 384.f);
  const float var = sq * (1.f / 384.f) - mean * mean;
  const float rstd = rsqrtf(var + 1e-5f);
  size_t dst;
  if constexpr (WIN) {
    int b = tok / 3136, l = tok - b * 3136;
    int i = l / 56, j = l - i * 56;
    int hp = i - 3; if (hp < 0) hp += 56;
    int wp = j - 3; if (wp < 0) wp += 56;
    int wi = (hp / 7) * 8 + wp / 7;
    int n = (hp % 7) * 7 + wp % 7;
    dst = (size_t)(b * 64 + wi) * 49 + n;
  } else {
    dst = (size_t)tok;
  }
  unsigned int* o = (unsigned int*)(out + dst * 384);
  const float2* G = (const float2*)gm;
  const float2* Bv = (const float2*)bt;
#pragma unroll
  for (int i = 0; i < 3; ++i) {
    int j = lane + 64 * i;
    float2 gv = G[j], bv = Bv[j];
    float a = (v[i].x - mean) * rstd * gv.x + bv.x;
    float b2 = (v[i].y - mean) * rstd * gv.y + bv.y;
    o[j] = (unsigned)f2u(a) | ((unsigned)f2u(b2) << 16);
  }
}

// ---------- fused window attention: one block per window, barrier-free per-wave LDS ----------
__global__ __launch_bounds__(256, 3) void attn_kernel(const __hip_bfloat16* __restrict__ xn,
                                                      const __hip_bfloat16* __restrict__ wq,
                                                      const float* __restrict__ qb,
                                                      const float* __restrict__ rpb,
                                                      __hip_bfloat16* __restrict__ ao) {
  const int win = blockIdx.x;        // 0..2047
  const int widx = win & 63;         // window-in-image
  const int lane = threadIdx.x & 63, wave = threadIdx.x >> 6;
  const int g = lane >> 4, r = lane & 15;
  const int wbh = (widx >> 3) * 7, wbw = (widx & 7) * 7;

  // per-wave LDS slice (12448 B): q [49][40] @0, k [49][40] @3920, vT [32][72] @7840
  // P [49][72] (7056 B) overlays q+k after phase 2. No cross-wave sharing -> no barriers.
  __shared__ __align__(16) char lds_all[4][12448];
  __hip_bfloat16* q_l = (__hip_bfloat16*)&lds_all[wave][0];
  __hip_bfloat16* k_l = (__hip_bfloat16*)&lds_all[wave][3920];
  __hip_bfloat16* vT = (__hip_bfloat16*)&lds_all[wave][7840];
  __hip_bfloat16* P_l = (__hip_bfloat16*)&lds_all[wave][0];

  bf16x8 zf;
#pragma unroll
  for (int i = 0; i < 8; ++i) zf[i] = tobf(0.f);

  // zero vT pad tokens 48..63 (read by PV under P=0; must be finite)
  for (int i = lane; i < 512; i += 64) {
    int d = i >> 4, t = 48 + (i & 15);
    vT[d * 72 + t] = __float2bfloat16(0.f);
  }

  // column geometry (depends only on r)
  int yj4[4], xj4[4], rj4[4];
  bool val4[4];
#pragma unroll
  for (int nt = 0; nt < 4; ++nt) {
    int jt = nt * 16 + r;
    val4[nt] = jt < 49;
    int jc = val4[nt] ? jt : 0;
    int yj = jc / 7, xj = jc - yj * 7;
    yj4[nt] = yj; xj4[nt] = xj;
    int hj = wbh + yj, wj = wbw + xj;
    rj4[nt] = (hj < 49 ? 0 : (hj < 53 ? 1 : 2)) * 3 + (wj < 49 ? 0 : (wj < 53 ? 1 : 2));
  }

  for (int hh = 0; hh < 3; ++hh) {
    const int head = hh * 4 + wave;
    // ---- phase 1: qkv for this head, s-outer to keep acc small ----
#pragma unroll
    for (int s = 0; s < 3; ++s) {
      f32x4 acc[4][2] = {};
      for (int kk = 0; kk < 12; ++kk) {
        const int kb = kk * 32 + g * 8;
        bf16x8 af[4];
#pragma unroll
        for (int mt = 0; mt < 4; ++mt) {
          int t = mt * 16 + r;
          af[mt] = (t < 49) ? *(const bf16x8*)(xn + ((size_t)win * 49 + t) * 384 + kb) : zf;
        }
#pragma unroll
        for (int nt = 0; nt < 2; ++nt) {
          bf16x8 bw = *(const bf16x8*)(wq + (size_t)(s * 384 + head * 32 + nt * 16 + r) * 384 + kb);
#pragma unroll
          for (int mt = 0; mt < 4; ++mt)
            acc[mt][nt] = __builtin_amdgcn_mfma_f32_16x16x32_bf16(af[mt], bw, acc[mt][nt], 0, 0, 0);
        }
      }
#pragma unroll
      for (int mt = 0; mt < 4; ++mt)
#pragma unroll
        for (int nt = 0; nt < 2; ++nt)
#pragma unroll
          for (int j = 0; j < 4; ++j) {
            int row = mt * 16 + g * 4 + j, col = nt * 16 + r;
            if (row < 49) {
              float v = acc[mt][nt][j] + qb[s * 384 + head * 32 + col];
              if (s == 0) q_l[row * 40 + col] = __float2bfloat16(v * SCALE_);
              else if (s == 1) k_l[row * 40 + col] = __float2bfloat16(v);
              else vT[col * 72 + row] = __float2bfloat16(v);
            }
          }
    }
    // ---- phase 2: S = q @ k^T ----
    f32x4 sA[4][4] = {};
    {
      bf16x8 qa[4];
#pragma unroll
      for (int mt = 0; mt < 4; ++mt) {
        int row = mt * 16 + r;
        qa[mt] = (row < 49) ? *(const bf16x8*)(q_l + row * 40 + g * 8) : zf;
      }
#pragma unroll
      for (int nt = 0; nt < 4; ++nt) {
        int rowk = nt * 16 + r;
        bf16x8 kf = (rowk < 49) ? *(const bf16x8*)(k_l + rowk * 40 + g * 8) : zf;
#pragma unroll
        for (int mt = 0; mt < 4; ++mt)
          sA[mt][nt] = __builtin_amdgcn_mfma_f32_16x16x32_bf16(qa[mt], kf, sA[mt][nt], 0, 0, 0);
      }
    }
    // ---- softmax (+rpb +shift mask) fused with P write ----
#pragma unroll
    for (int mt = 0; mt < 4; ++mt) {
#pragma unroll
      for (int j = 0; j < 4; ++j) {
        const int it = mt * 16 + g * 4 + j;
        if (it < 49) {
          int yi = it / 7, xi = it - yi * 7;
          int hi = wbh + yi, wi2 = wbw + xi;
          int ri = (hi < 49 ? 0 : (hi < 53 ? 1 : 2)) * 3 + (wi2 < 49 ? 0 : (wi2 < 53 ? 1 : 2));
          float v4[4];
#pragma unroll
          for (int nt = 0; nt < 4; ++nt) {
            float sv = -1e30f;
            if (val4[nt]) {
              sv = sA[mt][nt][j] +
                   rpb[((yi - yj4[nt] + 6) * 13 + (xi - xj4[nt] + 6)) * 12 + head];
              if (ri != rj4[nt]) sv -= 100.f;
            }
            v4[nt] = sv;
          }
          float mx = fmaxf(fmaxf(v4[0], v4[1]), fmaxf(v4[2], v4[3]));
#pragma unroll
          for (int m = 1; m < 16; m <<= 1) mx = fmaxf(mx, __shfl_xor(mx, m, 64));
          float sum = 0.f;
#pragma unroll
          for (int nt = 0; nt < 4; ++nt) { v4[nt] = __expf(v4[nt] - mx); sum += v4[nt]; }
#pragma unroll
          for (int m = 1; m < 16; m <<= 1) sum += __shfl_xor(sum, m, 64);
          float inv = 1.f / sum;
#pragma unroll
          for (int nt = 0; nt < 4; ++nt)
            P_l[it * 72 + nt * 16 + r] = __float2bfloat16(v4[nt] * inv);
        }
      }
    }
    // ---- phase 3: out = P @ V ----
    f32x4 oA[4][2] = {};
#pragma unroll
    for (int ks = 0; ks < 2; ++ks) {
      bf16x8 pa[4];
#pragma unroll
      for (int mt = 0; mt < 4; ++mt) {
        int row = mt * 16 + r;
        pa[mt] = (row < 49) ? *(const bf16x8*)(P_l + row * 72 + ks * 32 + g * 8) : zf;
      }
#pragma unroll
      for (int nt = 0; nt < 2; ++nt) {
        bf16x8 vb = *(const bf16x8*)(vT + (nt * 16 + r) * 72 + ks * 32 + g * 8);
#pragma unroll
        for (int mt = 0; mt < 4; ++mt)
          oA[mt][nt] = __builtin_amdgcn_mfma_f32_16x16x32_bf16(pa[mt], vb, oA[mt][nt], 0, 0, 0);
      }
    }
#pragma unroll
    for (int mt = 0; mt < 4; ++mt)
#pragma unroll
      for (int nt = 0; nt < 2; ++nt)
#pragma unroll
        for (int j = 0; j < 4; ++j) {
          int row = mt * 16 + g * 4 + j;
          if (row < 49)
            ao[((size_t)win * 49 + row) * 384 + head * 32 + nt * 16 + r] =
                __float2bfloat16(oA[mt][nt][j]);
        }
  }
}

// ---------- generic MFMA GEMM: out[M x N] = A[M x KD] @ W^T, fused epilogues ----------
enum { EPI_PROJ = 0, EPI_SE1 = 1, EPI_SE2 = 2, EPI_C1 = 3, EPI_C2 = 4 };

template <int EPI, int KD, int NT, bool AF32>
__global__ __launch_bounds__(256) void gemm_k(const void* Ap, const __hip_bfloat16* __restrict__ W,
                                              const float* __restrict__ bias, const float* p0,
                                              const float* p1, const float* p2, void* outp) {
  const int lane = threadIdx.x & 63;
  const int wave = threadIdx.x >> 6;
  const int g = lane >> 4, r = lane & 15;
  const int row0 = blockIdx.x * 64;
  const int n0 = wave * (NT * 16);

  f32x4 acc[NT][4] = {};

  for (int kk = 0; kk < KD / 32; ++kk) {
    const int kb = kk * 32 + g * 8;
    bf16x8 af[4];
    if constexpr (AF32) {
      const float* A = (const float*)Ap;
#pragma unroll
      for (int mt = 0; mt < 4; ++mt) {
        const float4* s = (const float4*)(A + (size_t)(row0 + mt * 16 + r) * KD + kb);
        float4 a = s[0], b = s[1];
        bf16x8 t;
        t[0] = tobf(a.x); t[1] = tobf(a.y); t[2] = tobf(a.z); t[3] = tobf(a.w);
        t[4] = tobf(b.x); t[5] = tobf(b.y); t[6] = tobf(b.z); t[7] = tobf(b.w);
        af[mt] = t;
      }
    } else {
      const __hip_bfloat16* A = (const __hip_bfloat16*)Ap;
#pragma unroll
      for (int mt = 0; mt < 4; ++mt)
        af[mt] = *(const bf16x8*)(A + (size_t)(row0 + mt * 16 + r) * KD + kb);
    }
#pragma unroll
    for (int nt = 0; nt < NT; ++nt) {
      bf16x8 bf = *(const bf16x8*)(W + (size_t)(n0 + nt * 16 + r) * KD + kb);
#pragma unroll
      for (int mt = 0; mt < 4; ++mt)
        acc[nt][mt] = __builtin_amdgcn_mfma_f32_16x16x32_bf16(af[mt], bf, acc[nt][mt], 0, 0, 0);
    }
  }

#pragma unroll
  for (int mt = 0; mt < 4; ++mt) {
#pragma unroll
    for (int j = 0; j < 4; ++j) {
      const int row = row0 + mt * 16 + g * 4 + j;
      size_t obase;
      if constexpr (EPI == EPI_PROJ) {
        int wi = row / 49, n = row - wi * 49;
        int b = wi >> 6, widx = wi & 63;
        int n7 = n / 7;
        int hp = (widx >> 3) * 7 + n7, wp = (widx & 7) * 7 + (n - n7 * 7);
        int ii = hp + 3; if (ii >= 56) ii -= 56;
        int jj = wp + 3; if (jj >= 56) jj -= 56;
        obase = ((size_t)b * 3136 + ii * 56 + jj) * 384;
      } else {
        obase = (size_t)row * (EPI == EPI_SE1 ? 192 : 384);
      }
#pragma unroll
      for (int nt = 0; nt < NT; ++nt) {
        const int col = n0 + nt * 16 + r;
        float v = acc[nt][mt][j] + bias[col];
        if constexpr (EPI == EPI_PROJ) {
          ((float*)outp)[obase + col] = p0[obase + col] + v;  // residual add (shortcut x)
        } else if constexpr (EPI == EPI_SE1) {
          ((__hip_bfloat16*)outp)[obase + col] = __float2bfloat16(fmaxf(v, 0.f));
        } else if constexpr (EPI == EPI_SE2) {
          float gate = 1.f / (1.f + __expf(-v));
          ((float*)outp)[obase + col] = p0[obase + col] * gate;  // x2 = x1*sigmoid (in-place ok)
        } else if constexpr (EPI == EPI_C1) {
          float gl = 0.5f * v * (1.f + erff(v * 0.70710678118654752f));
          ((__hip_bfloat16*)outp)[obase + col] = __float2bfloat16(gl * p0[col] + p1[col]);
        } else {  // EPI_C2
          float y = v * p0[col] + p1[col];
          ((float*)outp)[obase + col] = p2[obase + col] + y;  // final = x2 + y (in-place ok)
        }
      }
    }
  }
}

// ---------- depthwise 3x3 (NHWC) + gelu*bn2 — register sliding window, 14 outputs/thread ----------
__global__ __launch_bounds__(256) void dw_kernel(const __hip_bfloat16* __restrict__ y1,
                                                 const float* __restrict__ wt,  // [9][384]
                                                 const float* __restrict__ wb,
                                                 const float* __restrict__ g2,
                                                 const float* __restrict__ b2,
                                                 __hip_bfloat16* __restrict__ y2) {
  const int tid = blockIdx.x * 256 + threadIdx.x;  // 32*56*4*48 = 344064
  const int c8 = tid % 48;
  int t = tid / 48;
  const int q = t & 3; t >>= 2;
  const int hq = t % 56;
  const int b = t / 56;
  const int cb = c8 * 8;
  const int x0 = q * 14;

  float wr[9][8];
#pragma unroll
  for (int k = 0; k < 9; ++k) {
    float4 a = *(const float4*)(wt + k * 384 + cb);
    float4 c = *(const float4*)(wt + k * 384 + cb + 4);
    wr[k][0] = a.x; wr[k][1] = a.y; wr[k][2] = a.z; wr[k][3] = a.w;
    wr[k][4] = c.x; wr[k][5] = c.y; wr[k][6] = c.z; wr[k][7] = c.w;
  }
  if (hq == 0) {
#pragma unroll
    for (int k = 0; k < 3; ++k)
#pragma unroll
      for (int i = 0; i < 8; ++i) wr[k][i] = 0.f;
  }
  if (hq == 55) {
#pragma unroll
    for (int k = 6; k < 9; ++k)
#pragma unroll
      for (int i = 0; i < 8; ++i) wr[k][i] = 0.f;
  }
  float bias[8], gv[8], bv[8];
  {
    float4 a = *(const float4*)(wb + cb), c = *(const float4*)(wb + cb + 4);
    bias[0] = a.x; bias[1] = a.y; bias[2] = a.z; bias[3] = a.w;
    bias[4] = c.x; bias[5] = c.y; bias[6] = c.z; bias[7] = c.w;
    float4 d = *(const float4*)(g2 + cb), e = *(const float4*)(g2 + cb + 4);
    gv[0] = d.x; gv[1] = d.y; gv[2] = d.z; gv[3] = d.w;
    gv[4] = e.x; gv[5] = e.y; gv[6] = e.z; gv[7] = e.w;
    float4 f = *(const float4*)(b2 + cb), h = *(const float4*)(b2 + cb + 4);
    bv[0] = f.x; bv[1] = f.y; bv[2] = f.z; bv[3] = f.w;
    bv[4] = h.x; bv[5] = h.y; bv[6] = h.z; bv[7] = h.w;
  }
  const int hm = hq > 0 ? hq - 1 : 0;
  const int hp = hq < 55 ? hq + 1 : 55;
  const __hip_bfloat16* r0 = y1 + ((size_t)(b * 3136 + hm * 56)) * 384 + cb;
  const __hip_bfloat16* r1 = y1 + ((size_t)(b * 3136 + hq * 56)) * 384 + cb;
  const __hip_bfloat16* r2 = y1 + ((size_t)(b * 3136 + hp * 56)) * 384 + cb;
  __hip_bfloat16* op = y2 + ((size_t)(b * 3136 + hq * 56)) * 384 + cb;

  u16x8 zv;
#pragma unroll
  for (int i = 0; i < 8; ++i) zv[i] = 0;
#define LDC(rp, x) (((unsigned)(x) < 56u) ? *(const u16x8*)((rp) + (size_t)(x) * 384) : zv)

  u16x8 L0 = LDC(r0, x0 - 1), L1 = LDC(r1, x0 - 1), L2 = LDC(r2, x0 - 1);
  u16x8 C0 = LDC(r0, x0), C1 = LDC(r1, x0), C2 = LDC(r2, x0);
#pragma unroll
  for (int xi = 0; xi < 14; ++xi) {
    const int x = x0 + xi;
    u16x8 R0 = LDC(r0, x + 1), R1 = LDC(r1, x + 1), R2 = LDC(r2, x + 1);
    float acc[8];
#pragma unroll
    for (int i = 0; i < 8; ++i) acc[i] = bias[i];
#pragma unroll
    for (int i = 0; i < 8; ++i) {
      acc[i] += __uint_as_float((unsigned)L0[i] << 16) * wr[0][i];
      acc[i] += __uint_as_float((unsigned)C0[i] << 16) * wr[1][i];
      acc[i] += __uint_as_float((unsigned)R0[i] << 16) * wr[2][i];
      acc[i] += __uint_as_float((unsigned)L1[i] << 16) * wr[3][i];
      acc[i] += __uint_as_float((unsigned)C1[i] << 16) * wr[4][i];
      acc[i] += __uint_as_float((unsigned)R1[i] << 16) * wr[5][i];
      acc[i] += __uint_as_float((unsigned)L2[i] << 16) * wr[6][i];
      acc[i] += __uint_as_float((unsigned)C2[i] << 16) * wr[7][i];
      acc[i] += __uint_as_float((unsigned)R2[i] << 16) * wr[8][i];
    }
    u16x8 o;
#pragma unroll
    for (int i = 0; i < 8; ++i) {
      float u = acc[i];
      float gl = 0.5f * u * (1.f + erff(u * 0.70710678118654752f));
      o[i] = f2u(gl * gv[i] + bv[i]);
    }
    *(u16x8*)(op + (size_t)x * 384) = o;
    L0 = C0; L1 = C1; L2 = C2;
    C0 = R0; C1 = R1; C2 = R2;
  }
#undef LDC
}

extern "C" void kernel_launch(void* const* d_in, const int* in_sizes, int n_in, void* d_out,
                              int out_size, void* d_ws, size_t ws_size, hipStream_t stream) {
  (void)in_sizes; (void)n_in; (void)out_size; (void)ws_size;
  const float* x = (const float*)d_in[0];
  const float* n1g = (const float*)d_in[1];
  const float* n1b = (const float*)d_in[2];
  const float* qkv_w = (const float*)d_in[3];
  const float* qkv_b = (const float*)d_in[4];
  const float* rpb = (const float*)d_in[5];
  const float* proj_w = (const float*)d_in[6];
  const float* proj_b = (const float*)d_in[7];
  const float* se1_w = (const float*)d_in[8];
  const float* se1_b = (const float*)d_in[9];
  const float* se2_w = (const float*)d_in[10];
  const float* se2_b = (const float*)d_in[11];
  const float* n2g = (const float*)d_in[12];
  const float* n2b = (const float*)d_in[13];
  const float* c1_w = (const float*)d_in[14];
  const float* c1_b = (const float*)d_in[15];
  const float* bn1g = (const float*)d_in[16];
  const float* bn1b = (const float*)d_in[17];
  const float* dw_w = (const float*)d_in[18];
  const float* dw_b = (const float*)d_in[19];
  const float* bn2g = (const float*)d_in[20];
  const float* bn2b = (const float*)d_in[21];
  const float* c2_w = (const float*)d_in[22];
  const float* c2_b = (const float*)d_in[23];
  const float* bn3g = (const float*)d_in[24];
  const float* bn3b = (const float*)d_in[25];

  char* ws = (char*)d_ws;
  __hip_bfloat16* xn = (__hip_bfloat16*)(ws + OFF_XN);
  __hip_bfloat16* ao = (__hip_bfloat16*)(ws + OFF_AO);
  __hip_bfloat16* wbp = (__hip_bfloat16*)(ws + OFF_WB);
  float* wt = (float*)(ws + OFF_WT);
  __hip_bfloat16* qkv_wb = wbp;             // 442368
  __hip_bfloat16* proj_wb = wbp + 442368;   // 147456
  __hip_bfloat16* se1_wb = wbp + 589824;    // 73728
  __hip_bfloat16* se2_wb = wbp + 663552;    // 73728
  __hip_bfloat16* c1_wb = wbp + 737280;     // 147456
  __hip_bfloat16* c2_wb = wbp + 884736;     // 147456
  float* out = (float*)d_out;

  cvt_kernel<<<1728, 256, 0, stream>>>(qkv_w, qkv_wb, 442368);
  cvt_kernel<<<576, 256, 0, stream>>>(proj_w, proj_wb, 147456);
  cvt_kernel<<<288, 256, 0, stream>>>(se1_w, se1_wb, 73728);
  cvt_kernel<<<288, 256, 0, stream>>>(se2_w, se2_wb, 73728);
  cvt_kernel<<<576, 256, 0, stream>>>(c1_w, c1_wb, 147456);
  cvt_kernel<<<576, 256, 0, stream>>>(c2_w, c2_wb, 147456);
  dwrep_kernel<<<14, 256, 0, stream>>>(dw_w, wt);

  // LN1 + shift + window partition -> xn (bf16, windowed)
  ln_kernel<true><<<25088, 256, 0, stream>>>(x, n1g, n1b, xn);
  // fused window attention -> ao (bf16, windowed)
  attn_kernel<<<2048, 256, 0, stream>>>(xn, qkv_wb, qkv_b, rpb, ao);
  // proj + window-reverse + roll-back + residual -> x1 (fp32, in d_out)
  gemm_k<EPI_PROJ, 384, 6, false><<<1568, 256, 0, stream>>>(ao, proj_wb, proj_b, x, nullptr,
                                                            nullptr, out);
  // SE: g1 = relu(x1 @ se1^T) -> ao (bf16 [M][192])
  gemm_k<EPI_SE1, 384, 3, true><<<1568, 256, 0, stream>>>(out, se1_wb, se1_b, nullptr, nullptr,
                                                          nullptr, ao);
  // x2 = x1 * sigmoid(g1 @ se2^T) -> d_out (in place)
  gemm_k<EPI_SE2, 192, 6, false><<<1568, 256, 0, stream>>>(ao, se2_wb, se2_b, out, nullptr,
                                                           nullptr, out);
  // LN2 -> xn (bf16, plain token order)
  ln_kernel<false><<<25088, 256, 0, stream>>>(out, n2g, n2b, xn);
  // y1 = gelu(xn @ c1^T)*bn1 -> ao
  gemm_k<EPI_C1, 384, 6, false><<<1568, 256, 0, stream>>>(xn, c1_wb, c1_b, bn1g, bn1b, nullptr,
                                                          ao);
  // y2 = gelu(dwconv(y1))*bn2 -> xn
  dw_kernel<<<1344, 256, 0, stream>>>(ao, wt, dw_b, bn2g, bn2b, xn);
  // out = x2 + (y2 @ c2^T)*bn3 -> d_out (in place)
  gemm_k<EPI_C2, 384, 6, false><<<1568, 256, 0, stream>>>(xn, c2_wb, c2_b, bn3g, bn3b, out, out);
}

// Round 4
// 2009.609 us; speedup vs baseline: 1.0630x; 1.0630x over previous
//
#include <hip/hip_runtime.h>
#include <hip/hip_bf16.h>

typedef __attribute__((ext_vector_type(4))) float f32x4;
typedef __attribute__((ext_vector_type(8))) __bf16 bf16x8;
typedef __attribute__((ext_vector_type(8))) unsigned short u16x8;

#define SCALE_ 0.17677669529663687f  /* 32^-0.5 */

// ---------- workspace layout (bytes) ----------
#define OFF_XN 0ull                  // bf16 [100352][384]  (windowed LN1 out; later y2)
#define OFF_AO 77070336ull           // bf16 [100352][384]  (attn out; later g1, y1)
#define OFF_WB 154140672ull          // bf16 weight copies (1,032,192 elems)
#define OFF_WT 156205056ull          // f32 [9][384] repacked dw weights (13824 B)

__device__ __forceinline__ __bf16 tobf(float f) {
  __hip_bfloat16 h = __float2bfloat16(f);
  return __builtin_bit_cast(__bf16, h);
}
__device__ __forceinline__ unsigned short f2u(float f) {
  return __builtin_bit_cast(unsigned short, __float2bfloat16(f));
}

// ---------- fp32 -> bf16 weight copy ----------
__global__ __launch_bounds__(256) void cvt_kernel(const float* __restrict__ src,
                                                  __hip_bfloat16* __restrict__ dst, int n) {
  int i = blockIdx.x * 256 + threadIdx.x;
  int stride = gridDim.x * 256;
  for (; i < n; i += stride) dst[i] = __float2bfloat16(src[i]);
}

// ---------- repack dw weights [384][9] -> [9][384] ----------
__global__ __launch_bounds__(256) void dwrep_kernel(const float* __restrict__ src,
                                                    float* __restrict__ dst) {
  int i = blockIdx.x * 256 + threadIdx.x;
  if (i < 3456) {
    int c = i / 9, k = i - c * 9;
    dst[k * 384 + c] = src[i];
  }
}

// ---------- LayerNorm (one wave per token); WIN: write to rolled+windowed position ----------
template <bool WIN>
__global__ __launch_bounds__(256) void ln_kernel(const float* __restrict__ x,
                                                 const float* __restrict__ gm,
                                                 const float* __restrict__ bt,
                                                 __hip_bfloat16* __restrict__ out) {
  const int tok = blockIdx.x * 4 + (threadIdx.x >> 6);
  const int lane = threadIdx.x & 63;
  const float2* row = (const float2*)(x + (size_t)tok * 384);
  float2 v[3];
  v[0] = row[lane]; v[1] = row[lane + 64]; v[2] = row[lane + 128];
  float s = 0.f, sq = 0.f;
#pragma unroll
  for (int i = 0; i < 3; ++i) { s += v[i].x + v[i].y; sq += v[i].x * v[i].x + v[i].y * v[i].y; }
#pragma unroll
  for (int m = 1; m < 64; m <<= 1) { s += __shfl_xor(s, m, 64); sq += __shfl_xor(sq, m, 64); }
  const float mean = s * (1.f / 384.f);
  const float var = sq * (1.f / 384.f) - mean * mean;
  const float rstd = rsqrtf(var + 1e-5f);
  size_t dst;
  if constexpr (WIN) {
    int b = tok / 3136, l = tok - b * 3136;
    int i = l / 56, j = l - i * 56;
    int hp = i - 3; if (hp < 0) hp += 56;
    int wp = j - 3; if (wp < 0) wp += 56;
    int wi = (hp / 7) * 8 + wp / 7;
    int n = (hp % 7) * 7 + wp % 7;
    dst = (size_t)(b * 64 + wi) * 49 + n;
  } else {
    dst = (size_t)tok;
  }
  unsigned int* o = (unsigned int*)(out + dst * 384);
  const float2* G = (const float2*)gm;
  const float2* Bv = (const float2*)bt;
#pragma unroll
  for (int i = 0; i < 3; ++i) {
    int j = lane + 64 * i;
    float2 gv = G[j], bv = Bv[j];
    float a = (v[i].x - mean) * rstd * gv.x + bv.x;
    float b2 = (v[i].y - mean) * rstd * gv.y + bv.y;
    o[j] = (unsigned)f2u(a) | ((unsigned)f2u(b2) << 16);
  }
}

// ---------- fused window attention: one block per window, barrier-free per-wave LDS ----------
// Register discipline: phase-1 half-split keeps acc at 48 regs; peak (phase 2) ~130-150.
// launch_bounds(256,2) caps at 256 (no spill); natural usage <=170 -> 3 waves/SIMD possible.
__global__ __launch_bounds__(256, 2) void attn_kernel(const __hip_bfloat16* __restrict__ xn,
                                                      const __hip_bfloat16* __restrict__ wq,
                                                      const float* __restrict__ qb,
                                                      const float* __restrict__ rpb,
                                                      __hip_bfloat16* __restrict__ ao) {
  const int win = blockIdx.x;        // 0..2047
  const int widx = win & 63;         // window-in-image
  const int lane = threadIdx.x & 63, wave = threadIdx.x >> 6;
  const int g = lane >> 4, r = lane & 15;
  const int wbh = (widx >> 3) * 7, wbw = (widx & 7) * 7;

  // per-wave LDS slice (12448 B): q [49][40] @0, k [49][40] @3920, vT [32][72] @7840
  // P [49][72] (7056 B) overlays q+k after phase 2. No cross-wave sharing -> no barriers.
  __shared__ __align__(16) char lds_all[4][12448];
  __hip_bfloat16* q_l = (__hip_bfloat16*)&lds_all[wave][0];
  __hip_bfloat16* k_l = (__hip_bfloat16*)&lds_all[wave][3920];
  __hip_bfloat16* vT = (__hip_bfloat16*)&lds_all[wave][7840];
  __hip_bfloat16* P_l = (__hip_bfloat16*)&lds_all[wave][0];

  bf16x8 zf;
#pragma unroll
  for (int i = 0; i < 8; ++i) zf[i] = tobf(0.f);

  // zero vT pad tokens 48..63 (read by PV under P=0; must be finite)
  for (int i = lane; i < 512; i += 64) {
    int d = i >> 4, t = 48 + (i & 15);
    vT[d * 72 + t] = __float2bfloat16(0.f);
  }

  // column geometry (depends only on r)
  int yj4[4], xj4[4], rj4[4];
  bool val4[4];
#pragma unroll
  for (int nt = 0; nt < 4; ++nt) {
    int jt = nt * 16 + r;
    val4[nt] = jt < 49;
    int jc = val4[nt] ? jt : 0;
    int yj = jc / 7, xj = jc - yj * 7;
    yj4[nt] = yj; xj4[nt] = xj;
    int hj = wbh + yj, wj = wbw + xj;
    rj4[nt] = (hj < 49 ? 0 : (hj < 53 ? 1 : 2)) * 3 + (wj < 49 ? 0 : (wj < 53 ? 1 : 2));
  }

  for (int hh = 0; hh < 3; ++hh) {
    const int head = hh * 4 + wave;
    // ---- phase 1: qkv, two 32-row halves; A-frags shared across q/k/v ----
#pragma unroll
    for (int half = 0; half < 2; ++half) {
      f32x4 acc[3][2][2] = {};
      for (int kk = 0; kk < 12; ++kk) {
        const int kb = kk * 32 + g * 8;
        bf16x8 af[2];
#pragma unroll
        for (int mt = 0; mt < 2; ++mt) {
          int t = half * 32 + mt * 16 + r;
          af[mt] = (t < 49) ? *(const bf16x8*)(xn + ((size_t)win * 49 + t) * 384 + kb) : zf;
        }
#pragma unroll
        for (int s = 0; s < 3; ++s) {
#pragma unroll
          for (int nt = 0; nt < 2; ++nt) {
            bf16x8 bw =
                *(const bf16x8*)(wq + (size_t)(s * 384 + head * 32 + nt * 16 + r) * 384 + kb);
#pragma unroll
            for (int mt = 0; mt < 2; ++mt)
              acc[s][mt][nt] =
                  __builtin_amdgcn_mfma_f32_16x16x32_bf16(af[mt], bw, acc[s][mt][nt], 0, 0, 0);
          }
        }
      }
#pragma unroll
      for (int s = 0; s < 3; ++s)
#pragma unroll
        for (int mt = 0; mt < 2; ++mt)
#pragma unroll
          for (int nt = 0; nt < 2; ++nt)
#pragma unroll
            for (int j = 0; j < 4; ++j) {
              int row = half * 32 + mt * 16 + g * 4 + j, col = nt * 16 + r;
              if (row < 49) {
                float v = acc[s][mt][nt][j] + qb[s * 384 + head * 32 + col];
                if (s == 0) q_l[row * 40 + col] = __float2bfloat16(v * SCALE_);
                else if (s == 1) k_l[row * 40 + col] = __float2bfloat16(v);
                else vT[col * 72 + row] = __float2bfloat16(v);
              }
            }
    }
    // ---- phase 2: S = q @ k^T ----
    f32x4 sA[4][4] = {};
    {
      bf16x8 qa[4];
#pragma unroll
      for (int mt = 0; mt < 4; ++mt) {
        int row = mt * 16 + r;
        qa[mt] = (row < 49) ? *(const bf16x8*)(q_l + row * 40 + g * 8) : zf;
      }
#pragma unroll
      for (int nt = 0; nt < 4; ++nt) {
        int rowk = nt * 16 + r;
        bf16x8 kf = (rowk < 49) ? *(const bf16x8*)(k_l + rowk * 40 + g * 8) : zf;
#pragma unroll
        for (int mt = 0; mt < 4; ++mt)
          sA[mt][nt] = __builtin_amdgcn_mfma_f32_16x16x32_bf16(qa[mt], kf, sA[mt][nt], 0, 0, 0);
      }
    }
    // ---- softmax (+rpb +shift mask) fused with P write ----
#pragma unroll
    for (int mt = 0; mt < 4; ++mt) {
#pragma unroll
      for (int j = 0; j < 4; ++j) {
        const int it = mt * 16 + g * 4 + j;
        if (it < 49) {
          int yi = it / 7, xi = it - yi * 7;
          int hi = wbh + yi, wi2 = wbw + xi;
          int ri = (hi < 49 ? 0 : (hi < 53 ? 1 : 2)) * 3 + (wi2 < 49 ? 0 : (wi2 < 53 ? 1 : 2));
          float v4[4];
#pragma unroll
          for (int nt = 0; nt < 4; ++nt) {
            float sv = -1e30f;
            if (val4[nt]) {
              sv = sA[mt][nt][j] +
                   rpb[((yi - yj4[nt] + 6) * 13 + (xi - xj4[nt] + 6)) * 12 + head];
              if (ri != rj4[nt]) sv -= 100.f;
            }
            v4[nt] = sv;
          }
          float mx = fmaxf(fmaxf(v4[0], v4[1]), fmaxf(v4[2], v4[3]));
#pragma unroll
          for (int m = 1; m < 16; m <<= 1) mx = fmaxf(mx, __shfl_xor(mx, m, 64));
          float sum = 0.f;
#pragma unroll
          for (int nt = 0; nt < 4; ++nt) { v4[nt] = __expf(v4[nt] - mx); sum += v4[nt]; }
#pragma unroll
          for (int m = 1; m < 16; m <<= 1) sum += __shfl_xor(sum, m, 64);
          float inv = 1.f / sum;
#pragma unroll
          for (int nt = 0; nt < 4; ++nt)
            P_l[it * 72 + nt * 16 + r] = __float2bfloat16(v4[nt] * inv);
        }
      }
    }
    // ---- phase 3: out = P @ V ----
    f32x4 oA[4][2] = {};
#pragma unroll
    for (int ks = 0; ks < 2; ++ks) {
      bf16x8 pa[4];
#pragma unroll
      for (int mt = 0; mt < 4; ++mt) {
        int row = mt * 16 + r;
        pa[mt] = (row < 49) ? *(const bf16x8*)(P_l + row * 72 + ks * 32 + g * 8) : zf;
      }
#pragma unroll
      for (int nt = 0; nt < 2; ++nt) {
        bf16x8 vb = *(const bf16x8*)(vT + (nt * 16 + r) * 72 + ks * 32 + g * 8);
#pragma unroll
        for (int mt = 0; mt < 4; ++mt)
          oA[mt][nt] = __builtin_amdgcn_mfma_f32_16x16x32_bf16(pa[mt], vb, oA[mt][nt], 0, 0, 0);
      }
    }
#pragma unroll
    for (int mt = 0; mt < 4; ++mt)
#pragma unroll
      for (int nt = 0; nt < 2; ++nt)
#pragma unroll
        for (int j = 0; j < 4; ++j) {
          int row = mt * 16 + g * 4 + j;
          if (row < 49)
            ao[((size_t)win * 49 + row) * 384 + head * 32 + nt * 16 + r] =
                __float2bfloat16(oA[mt][nt][j]);
        }
  }
}

// ---------- generic MFMA GEMM: out[M x N] = A[M x KD] @ W^T, fused epilogues ----------
enum { EPI_PROJ = 0, EPI_SE1 = 1, EPI_SE2 = 2, EPI_C1 = 3, EPI_C2 = 4 };

template <int EPI, int KD, int NT, bool AF32>
__global__ __launch_bounds__(256) void gemm_k(const void* Ap, const __hip_bfloat16* __restrict__ W,
                                              const float* __restrict__ bias, const float* p0,
                                              const float* p1, const float* p2, void* outp) {
  const int lane = threadIdx.x & 63;
  const int wave = threadIdx.x >> 6;
  const int g = lane >> 4, r = lane & 15;
  const int row0 = blockIdx.x * 64;
  const int n0 = wave * (NT * 16);

  f32x4 acc[NT][4] = {};

  for (int kk = 0; kk < KD / 32; ++kk) {
    const int kb = kk * 32 + g * 8;
    bf16x8 af[4];
    if constexpr (AF32) {
      const float* A = (const float*)Ap;
#pragma unroll
      for (int mt = 0; mt < 4; ++mt) {
        const float4* s = (const float4*)(A + (size_t)(row0 + mt * 16 + r) * KD + kb);
        float4 a = s[0], b = s[1];
        bf16x8 t;
        t[0] = tobf(a.x); t[1] = tobf(a.y); t[2] = tobf(a.z); t[3] = tobf(a.w);
        t[4] = tobf(b.x); t[5] = tobf(b.y); t[6] = tobf(b.z); t[7] = tobf(b.w);
        af[mt] = t;
      }
    } else {
      const __hip_bfloat16* A = (const __hip_bfloat16*)Ap;
#pragma unroll
      for (int mt = 0; mt < 4; ++mt)
        af[mt] = *(const bf16x8*)(A + (size_t)(row0 + mt * 16 + r) * KD + kb);
    }
#pragma unroll
    for (int nt = 0; nt < NT; ++nt) {
      bf16x8 bf = *(const bf16x8*)(W + (size_t)(n0 + nt * 16 + r) * KD + kb);
#pragma unroll
      for (int mt = 0; mt < 4; ++mt)
        acc[nt][mt] = __builtin_amdgcn_mfma_f32_16x16x32_bf16(af[mt], bf, acc[nt][mt], 0, 0, 0);
    }
  }

#pragma unroll
  for (int mt = 0; mt < 4; ++mt) {
#pragma unroll
    for (int j = 0; j < 4; ++j) {
      const int row = row0 + mt * 16 + g * 4 + j;
      size_t obase;
      if constexpr (EPI == EPI_PROJ) {
        int wi = row / 49, n = row - wi * 49;
        int b = wi >> 6, widx = wi & 63;
        int n7 = n / 7;
        int hp = (widx >> 3) * 7 + n7, wp = (widx & 7) * 7 + (n - n7 * 7);
        int ii = hp + 3; if (ii >= 56) ii -= 56;
        int jj = wp + 3; if (jj >= 56) jj -= 56;
        obase = ((size_t)b * 3136 + ii * 56 + jj) * 384;
      } else {
        obase = (size_t)row * (EPI == EPI_SE1 ? 192 : 384);
      }
#pragma unroll
      for (int nt = 0; nt < NT; ++nt) {
        const int col = n0 + nt * 16 + r;
        float v = acc[nt][mt][j] + bias[col];
        if constexpr (EPI == EPI_PROJ) {
          ((float*)outp)[obase + col] = p0[obase + col] + v;  // residual add (shortcut x)
        } else if constexpr (EPI == EPI_SE1) {
          ((__hip_bfloat16*)outp)[obase + col] = __float2bfloat16(fmaxf(v, 0.f));
        } else if constexpr (EPI == EPI_SE2) {
          float gate = 1.f / (1.f + __expf(-v));
          ((float*)outp)[obase + col] = p0[obase + col] * gate;  // x2 = x1*sigmoid (in-place ok)
        } else if constexpr (EPI == EPI_C1) {
          float gl = 0.5f * v * (1.f + erff(v * 0.70710678118654752f));
          ((__hip_bfloat16*)outp)[obase + col] = __float2bfloat16(gl * p0[col] + p1[col]);
        } else {  // EPI_C2
          float y = v * p0[col] + p1[col];
          ((float*)outp)[obase + col] = p2[obase + col] + y;  // final = x2 + y (in-place ok)
        }
      }
    }
  }
}

// ---------- depthwise 3x3 (NHWC) + gelu*bn2 — register sliding window, 14 outputs/thread ----------
__global__ __launch_bounds__(256) void dw_kernel(const __hip_bfloat16* __restrict__ y1,
                                                 const float* __restrict__ wt,  // [9][384]
                                                 const float* __restrict__ wb,
                                                 const float* __restrict__ g2,
                                                 const float* __restrict__ b2,
                                                 __hip_bfloat16* __restrict__ y2) {
  const int tid = blockIdx.x * 256 + threadIdx.x;  // 32*56*4*48 = 344064
  const int c8 = tid % 48;
  int t = tid / 48;
  const int q = t & 3; t >>= 2;
  const int hq = t % 56;
  const int b = t / 56;
  const int cb = c8 * 8;
  const int x0 = q * 14;

  float wr[9][8];
#pragma unroll
  for (int k = 0; k < 9; ++k) {
    float4 a = *(const float4*)(wt + k * 384 + cb);
    float4 c = *(const float4*)(wt + k * 384 + cb + 4);
    wr[k][0] = a.x; wr[k][1] = a.y; wr[k][2] = a.z; wr[k][3] = a.w;
    wr[k][4] = c.x; wr[k][5] = c.y; wr[k][6] = c.z; wr[k][7] = c.w;
  }
  if (hq == 0) {
#pragma unroll
    for (int k = 0; k < 3; ++k)
#pragma unroll
      for (int i = 0; i < 8; ++i) wr[k][i] = 0.f;
  }
  if (hq == 55) {
#pragma unroll
    for (int k = 6; k < 9; ++k)
#pragma unroll
      for (int i = 0; i < 8; ++i) wr[k][i] = 0.f;
  }
  float bias[8], gv[8], bv[8];
  {
    float4 a = *(const float4*)(wb + cb), c = *(const float4*)(wb + cb + 4);
    bias[0] = a.x; bias[1] = a.y; bias[2] = a.z; bias[3] = a.w;
    bias[4] = c.x; bias[5] = c.y; bias[6] = c.z; bias[7] = c.w;
    float4 d = *(const float4*)(g2 + cb), e = *(const float4*)(g2 + cb + 4);
    gv[0] = d.x; gv[1] = d.y; gv[2] = d.z; gv[3] = d.w;
    gv[4] = e.x; gv[5] = e.y; gv[6] = e.z; gv[7] = e.w;
    float4 f = *(const float4*)(b2 + cb), h = *(const float4*)(b2 + cb + 4);
    bv[0] = f.x; bv[1] = f.y; bv[2] = f.z; bv[3] = f.w;
    bv[4] = h.x; bv[5] = h.y; bv[6] = h.z; bv[7] = h.w;
  }
  const int hm = hq > 0 ? hq - 1 : 0;
  const int hp = hq < 55 ? hq + 1 : 55;
  const __hip_bfloat16* r0 = y1 + ((size_t)(b * 3136 + hm * 56)) * 384 + cb;
  const __hip_bfloat16* r1 = y1 + ((size_t)(b * 3136 + hq * 56)) * 384 + cb;
  const __hip_bfloat16* r2 = y1 + ((size_t)(b * 3136 + hp * 56)) * 384 + cb;
  __hip_bfloat16* op = y2 + ((size_t)(b * 3136 + hq * 56)) * 384 + cb;

  u16x8 zv;
#pragma unroll
  for (int i = 0; i < 8; ++i) zv[i] = 0;
#define LDC(rp, x) (((unsigned)(x) < 56u) ? *(const u16x8*)((rp) + (size_t)(x) * 384) : zv)

  u16x8 L0 = LDC(r0, x0 - 1), L1 = LDC(r1, x0 - 1), L2 = LDC(r2, x0 - 1);
  u16x8 C0 = LDC(r0, x0), C1 = LDC(r1, x0), C2 = LDC(r2, x0);
#pragma unroll
  for (int xi = 0; xi < 14; ++xi) {
    const int x = x0 + xi;
    u16x8 R0 = LDC(r0, x + 1), R1 = LDC(r1, x + 1), R2 = LDC(r2, x + 1);
    float acc[8];
#pragma unroll
    for (int i = 0; i < 8; ++i) acc[i] = bias[i];
#pragma unroll
    for (int i = 0; i < 8; ++i) {
      acc[i] += __uint_as_float((unsigned)L0[i] << 16) * wr[0][i];
      acc[i] += __uint_as_float((unsigned)C0[i] << 16) * wr[1][i];
      acc[i] += __uint_as_float((unsigned)R0[i] << 16) * wr[2][i];
      acc[i] += __uint_as_float((unsigned)L1[i] << 16) * wr[3][i];
      acc[i] += __uint_as_float((unsigned)C1[i] << 16) * wr[4][i];
      acc[i] += __uint_as_float((unsigned)R1[i] << 16) * wr[5][i];
      acc[i] += __uint_as_float((unsigned)L2[i] << 16) * wr[6][i];
      acc[i] += __uint_as_float((unsigned)C2[i] << 16) * wr[7][i];
      acc[i] += __uint_as_float((unsigned)R2[i] << 16) * wr[8][i];
    }
    u16x8 o;
#pragma unroll
    for (int i = 0; i < 8; ++i) {
      float u = acc[i];
      float gl = 0.5f * u * (1.f + erff(u * 0.70710678118654752f));
      o[i] = f2u(gl * gv[i] + bv[i]);
    }
    *(u16x8*)(op + (size_t)x * 384) = o;
    L0 = C0; L1 = C1; L2 = C2;
    C0 = R0; C1 = R1; C2 = R2;
  }
#undef LDC
}

extern "C" void kernel_launch(void* const* d_in, const int* in_sizes, int n_in, void* d_out,
                              int out_size, void* d_ws, size_t ws_size, hipStream_t stream) {
  (void)in_sizes; (void)n_in; (void)out_size; (void)ws_size;
  const float* x = (const float*)d_in[0];
  const float* n1g = (const float*)d_in[1];
  const float* n1b = (const float*)d_in[2];
  const float* qkv_w = (const float*)d_in[3];
  const float* qkv_b = (const float*)d_in[4];
  const float* rpb = (const float*)d_in[5];
  const float* proj_w = (const float*)d_in[6];
  const float* proj_b = (const float*)d_in[7];
  const float* se1_w = (const float*)d_in[8];
  const float* se1_b = (const float*)d_in[9];
  const float* se2_w = (const float*)d_in[10];
  const float* se2_b = (const float*)d_in[11];
  const float* n2g = (const float*)d_in[12];
  const float* n2b = (const float*)d_in[13];
  const float* c1_w = (const float*)d_in[14];
  const float* c1_b = (const float*)d_in[15];
  const float* bn1g = (const float*)d_in[16];
  const float* bn1b = (const float*)d_in[17];
  const float* dw_w = (const float*)d_in[18];
  const float* dw_b = (const float*)d_in[19];
  const float* bn2g = (const float*)d_in[20];
  const float* bn2b = (const float*)d_in[21];
  const float* c2_w = (const float*)d_in[22];
  const float* c2_b = (const float*)d_in[23];
  const float* bn3g = (const float*)d_in[24];
  const float* bn3b = (const float*)d_in[25];

  char* ws = (char*)d_ws;
  __hip_bfloat16* xn = (__hip_bfloat16*)(ws + OFF_XN);
  __hip_bfloat16* ao = (__hip_bfloat16*)(ws + OFF_AO);
  __hip_bfloat16* wbp = (__hip_bfloat16*)(ws + OFF_WB);
  float* wt = (float*)(ws + OFF_WT);
  __hip_bfloat16* qkv_wb = wbp;             // 442368
  __hip_bfloat16* proj_wb = wbp + 442368;   // 147456
  __hip_bfloat16* se1_wb = wbp + 589824;    // 73728
  __hip_bfloat16* se2_wb = wbp + 663552;    // 73728
  __hip_bfloat16* c1_wb = wbp + 737280;     // 147456
  __hip_bfloat16* c2_wb = wbp + 884736;     // 147456
  float* out = (float*)d_out;

  cvt_kernel<<<1728, 256, 0, stream>>>(qkv_w, qkv_wb, 442368);
  cvt_kernel<<<576, 256, 0, stream>>>(proj_w, proj_wb, 147456);
  cvt_kernel<<<288, 256, 0, stream>>>(se1_w, se1_wb, 73728);
  cvt_kernel<<<288, 256, 0, stream>>>(se2_w, se2_wb, 73728);
  cvt_kernel<<<576, 256, 0, stream>>>(c1_w, c1_wb, 147456);
  cvt_kernel<<<576, 256, 0, stream>>>(c2_w, c2_wb, 147456);
  dwrep_kernel<<<14, 256, 0, stream>>>(dw_w, wt);

  // LN1 + shift + window partition -> xn (bf16, windowed)
  ln_kernel<true><<<25088, 256, 0, stream>>>(x, n1g, n1b, xn);
  // fused window attention -> ao (bf16, windowed)
  attn_kernel<<<2048, 256, 0, stream>>>(xn, qkv_wb, qkv_b, rpb, ao);
  // proj + window-reverse + roll-back + residual -> x1 (fp32, in d_out)
  gemm_k<EPI_PROJ, 384, 6, false><<<1568, 256, 0, stream>>>(ao, proj_wb, proj_b, x, nullptr,
                                                            nullptr, out);
  // SE: g1 = relu(x1 @ se1^T) -> ao (bf16 [M][192])
  gemm_k<EPI_SE1, 384, 3, true><<<1568, 256, 0, stream>>>(out, se1_wb, se1_b, nullptr, nullptr,
                                                          nullptr, ao);
  // x2 = x1 * sigmoid(g1 @ se2^T) -> d_out (in place)
  gemm_k<EPI_SE2, 192, 6, false><<<1568, 256, 0, stream>>>(ao, se2_wb, se2_b, out, nullptr,
                                                           nullptr, out);
  // LN2 -> xn (bf16, plain token order)
  ln_kernel<false><<<25088, 256, 0, stream>>>(out, n2g, n2b, xn);
  // y1 = gelu(xn @ c1^T)*bn1 -> ao
  gemm_k<EPI_C1, 384, 6, false><<<1568, 256, 0, stream>>>(xn, c1_wb, c1_b, bn1g, bn1b, nullptr,
                                                          ao);
  // y2 = gelu(dwconv(y1))*bn2 -> xn
  dw_kernel<<<1344, 256, 0, stream>>>(ao, wt, dw_b, bn2g, bn2b, xn);
  // out = x2 + (y2 @ c2^T)*bn3 -> d_out (in place)
  gemm_k<EPI_C2, 384, 6, false><<<1568, 256, 0, stream>>>(xn, c2_wb, c2_b, bn3g, bn3b, out, out);
}

// Round 5
// 1160.757 us; speedup vs baseline: 1.8404x; 1.7313x over previous
//
#include <hip/hip_runtime.h>
#include <hip/hip_bf16.h>

typedef __attribute__((ext_vector_type(4))) float f32x4;
typedef __attribute__((ext_vector_type(8))) __bf16 bf16x8;
typedef __attribute__((ext_vector_type(8))) unsigned short u16x8;

#define SCALE_ 0.17677669529663687f  /* 32^-0.5 */

// ---------- workspace layout (bytes) ----------
// R0 [0, 77070336): xn (windowed LN1 out) -> attn out (ao) -> ln2 out -> y2
// R1 [77070336, 154140672): qkv chunk buf (63.7MB) -> g1 (38.5MB) -> y1 (77MB)
#define OFF_R1 77070336ull
#define OFF_WB 154140672ull          // bf16 weight copies (1,032,192 elems)
#define OFF_WT 156205056ull          // f32 [9][384] repacked dw weights (13824 B)

__device__ __forceinline__ __bf16 tobf(float f) {
  __hip_bfloat16 h = __float2bfloat16(f);
  return __builtin_bit_cast(__bf16, h);
}
__device__ __forceinline__ unsigned short f2u(float f) {
  return __builtin_bit_cast(unsigned short, __float2bfloat16(f));
}

// ---------- fp32 -> bf16 weight copy ----------
__global__ __launch_bounds__(256) void cvt_kernel(const float* __restrict__ src,
                                                  __hip_bfloat16* __restrict__ dst, int n) {
  int i = blockIdx.x * 256 + threadIdx.x;
  int stride = gridDim.x * 256;
  for (; i < n; i += stride) dst[i] = __float2bfloat16(src[i]);
}

// ---------- repack dw weights [384][9] -> [9][384] ----------
__global__ __launch_bounds__(256) void dwrep_kernel(const float* __restrict__ src,
                                                    float* __restrict__ dst) {
  int i = blockIdx.x * 256 + threadIdx.x;
  if (i < 3456) {
    int c = i / 9, k = i - c * 9;
    dst[k * 384 + c] = src[i];
  }
}

// ---------- LayerNorm (one wave per token); WIN: write to rolled+windowed position ----------
template <bool WIN>
__global__ __launch_bounds__(256) void ln_kernel(const float* __restrict__ x,
                                                 const float* __restrict__ gm,
                                                 const float* __restrict__ bt,
                                                 __hip_bfloat16* __restrict__ out) {
  const int tok = blockIdx.x * 4 + (threadIdx.x >> 6);
  const int lane = threadIdx.x & 63;
  const float2* row = (const float2*)(x + (size_t)tok * 384);
  float2 v[3];
  v[0] = row[lane]; v[1] = row[lane + 64]; v[2] = row[lane + 128];
  float s = 0.f, sq = 0.f;
#pragma unroll
  for (int i = 0; i < 3; ++i) { s += v[i].x + v[i].y; sq += v[i].x * v[i].x + v[i].y * v[i].y; }
#pragma unroll
  for (int m = 1; m < 64; m <<= 1) { s += __shfl_xor(s, m, 64); sq += __shfl_xor(sq, m, 64); }
  const float mean = s * (1.f / 384.f);
  const float var = sq * (1.f / 384.f) - mean * mean;
  const float rstd = rsqrtf(var + 1e-5f);
  size_t dst;
  if constexpr (WIN) {
    int b = tok / 3136, l = tok - b * 3136;
    int i = l / 56, j = l - i * 56;
    int hp = i - 3; if (hp < 0) hp += 56;
    int wp = j - 3; if (wp < 0) wp += 56;
    int wi = (hp / 7) * 8 + wp / 7;
    int n = (hp % 7) * 7 + wp % 7;
    dst = (size_t)(b * 64 + wi) * 49 + n;
  } else {
    dst = (size_t)tok;
  }
  unsigned int* o = (unsigned int*)(out + dst * 384);
  const float2* G = (const float2*)gm;
  const float2* Bv = (const float2*)bt;
#pragma unroll
  for (int i = 0; i < 3; ++i) {
    int j = lane + 64 * i;
    float2 gv = G[j], bv = Bv[j];
    float a = (v[i].x - mean) * rstd * gv.x + bv.x;
    float b2 = (v[i].y - mean) * rstd * gv.y + bv.y;
    o[j] = (unsigned)f2u(a) | ((unsigned)f2u(b2) << 16);
  }
}

// ---------- LDS-staged 128x128 GEMM: out = A[M][KD] @ W[N][KD]^T, fused epilogues ----------
enum { EPI_PROJ = 0, EPI_SE1 = 1, EPI_SE2 = 2, EPI_C1 = 3, EPI_C2 = 4, EPI_QKV = 5 };

template <int EPI, int KD, bool AF32>
__global__ __launch_bounds__(256) void gemm2(const void* __restrict__ Ap,
                                             const __hip_bfloat16* __restrict__ W,
                                             const float* __restrict__ bias,
                                             const float* __restrict__ p0,
                                             const float* __restrict__ p1,
                                             const float* __restrict__ p2,
                                             void* __restrict__ outp) {
  constexpr int NTOT = (EPI == EPI_QKV) ? 1152 : (EPI == EPI_SE1 ? 192 : 384);
  const int tid = threadIdx.x;
  const int lane = tid & 63, wave = tid >> 6;
  const int wm = wave >> 1, wn = wave & 1;
  const int g = lane >> 4, r = lane & 15;
  const int row0 = blockIdx.x * 128;
  const int col0 = blockIdx.y * 128;
  const int sr = tid >> 2;            // staging row 0..63 (per 64-row half)
  const int sc = (tid & 3) * 8;       // staging col (elems)

  // padded rows: 40 elems = 80B -> 16B aligned b128 ops, 2-way bank aliasing (free)
  __shared__ __align__(16) __hip_bfloat16 Al[128][40];
  __shared__ __align__(16) __hip_bfloat16 Bl[128][40];

  bf16x8 zf;
#pragma unroll
  for (int i = 0; i < 8; ++i) zf[i] = tobf(0.f);

  f32x4 acc[4][4] = {};  // [mt][nt]

  for (int kk = 0; kk < KD / 32; ++kk) {
    const int kb = kk * 32 + sc;
    // stage A (two 64-row halves)
#pragma unroll
    for (int h = 0; h < 2; ++h) {
      const int row = row0 + sr + h * 64;
      bf16x8 t;
      if constexpr (AF32) {
        const float* A = (const float*)Ap;
        const float4* sp = (const float4*)(A + (size_t)row * KD + kb);
        float4 a = sp[0], b = sp[1];
        t[0] = tobf(a.x); t[1] = tobf(a.y); t[2] = tobf(a.z); t[3] = tobf(a.w);
        t[4] = tobf(b.x); t[5] = tobf(b.y); t[6] = tobf(b.z); t[7] = tobf(b.w);
      } else {
        const __hip_bfloat16* A = (const __hip_bfloat16*)Ap;
        t = *(const bf16x8*)(A + (size_t)row * KD + kb);
      }
      *(bf16x8*)(&Al[sr + h * 64][sc]) = t;
    }
    // stage B (W rows = output cols), guard if N not multiple of 128
#pragma unroll
    for (int h = 0; h < 2; ++h) {
      const int wrow = col0 + sr + h * 64;
      bf16x8 t;
      if constexpr (NTOT % 128 != 0) {
        t = (wrow < NTOT) ? *(const bf16x8*)(W + (size_t)wrow * KD + kb) : zf;
      } else {
        t = *(const bf16x8*)(W + (size_t)wrow * KD + kb);
      }
      *(bf16x8*)(&Bl[sr + h * 64][sc]) = t;
    }
    __syncthreads();
    bf16x8 af[4], bf4[4];
#pragma unroll
    for (int mt = 0; mt < 4; ++mt) af[mt] = *(const bf16x8*)(&Al[wm * 64 + mt * 16 + r][g * 8]);
#pragma unroll
    for (int nt = 0; nt < 4; ++nt) bf4[nt] = *(const bf16x8*)(&Bl[wn * 64 + nt * 16 + r][g * 8]);
#pragma unroll
    for (int nt = 0; nt < 4; ++nt)
#pragma unroll
      for (int mt = 0; mt < 4; ++mt)
        acc[mt][nt] = __builtin_amdgcn_mfma_f32_16x16x32_bf16(af[mt], bf4[nt], acc[mt][nt], 0, 0, 0);
    __syncthreads();
  }

  // epilogue
#pragma unroll
  for (int mt = 0; mt < 4; ++mt) {
#pragma unroll
    for (int j = 0; j < 4; ++j) {
      const int row = row0 + wm * 64 + mt * 16 + g * 4 + j;
      size_t obase = 0;
      int win = 0, n = 0;
      if constexpr (EPI == EPI_PROJ) {
        int wi = row / 49, nn = row - wi * 49;
        int b = wi >> 6, widx = wi & 63;
        int n7 = nn / 7;
        int hp = (widx >> 3) * 7 + n7, wp = (widx & 7) * 7 + (nn - n7 * 7);
        int ii = hp + 3; if (ii >= 56) ii -= 56;
        int jj = wp + 3; if (jj >= 56) jj -= 56;
        obase = ((size_t)b * 3136 + ii * 56 + jj) * 384;
      } else if constexpr (EPI == EPI_QKV) {
        win = row / 49; n = row - win * 49;
      } else {
        obase = (size_t)row * (EPI == EPI_SE1 ? 192 : 384);
      }
#pragma unroll
      for (int nt = 0; nt < 4; ++nt) {
        const int col = col0 + wn * 64 + nt * 16 + r;
        if constexpr (NTOT % 128 != 0) { if (col >= NTOT) continue; }
        float v = acc[mt][nt][j] + bias[col];
        if constexpr (EPI == EPI_PROJ) {
          ((float*)outp)[obase + col] = p0[obase + col] + v;
        } else if constexpr (EPI == EPI_SE1) {
          ((__hip_bfloat16*)outp)[obase + col] = __float2bfloat16(fmaxf(v, 0.f));
        } else if constexpr (EPI == EPI_SE2) {
          float gate = 1.f / (1.f + __expf(-v));
          ((float*)outp)[obase + col] = p0[obase + col] * gate;
        } else if constexpr (EPI == EPI_C1) {
          float gl = 0.5f * v * (1.f + erff(v * 0.70710678118654752f));
          ((__hip_bfloat16*)outp)[obase + col] = __float2bfloat16(gl * p0[col] + p1[col]);
        } else if constexpr (EPI == EPI_C2) {
          float y = v * p0[col] + p1[col];
          ((float*)outp)[obase + col] = p2[obase + col] + y;
        } else {  // EPI_QKV: q[49][32] | k[49][32] | vT[32][64] per (win,head)
          const int s = col / 384, ch = col - s * 384;
          const int head = ch >> 5, d = ch & 31;
          __hip_bfloat16* qk = (__hip_bfloat16*)outp;
          const size_t hb = (size_t)win * 62208 + (size_t)head * 5184;
          if (s == 0) qk[hb + n * 32 + d] = __float2bfloat16(v * SCALE_);
          else if (s == 1) qk[hb + 1568 + n * 32 + d] = __float2bfloat16(v);
          else qk[hb + 3136 + d * 64 + n] = __float2bfloat16(v);
        }
      }
    }
  }
}

// ---------- attention core: one 64-thread block per (window, head) ----------
__global__ __launch_bounds__(64) void attn_core(const __hip_bfloat16* __restrict__ qkv,
                                                const float* __restrict__ rpb,
                                                __hip_bfloat16* __restrict__ ao, int win0) {
  const int bid = blockIdx.x;
  const int win_l = bid / 12, head = bid - win_l * 12;
  const int win = win0 + win_l;
  const int widx = win & 63;
  const int lane = threadIdx.x;
  const int g = lane >> 4, r = lane & 15;
  const int wbh = (widx >> 3) * 7, wbw = (widx & 7) * 7;
  const __hip_bfloat16* base = qkv + (size_t)win_l * 62208 + (size_t)head * 5184;

  // P [49][64] bf16, 16B chunks XOR-swizzled by (row&7)
  __shared__ __align__(16) __hip_bfloat16 P_l[49 * 64];

  bf16x8 zf;
#pragma unroll
  for (int i = 0; i < 8; ++i) zf[i] = tobf(0.f);

  // column geometry (depends only on r)
  int yj4[4], xj4[4], rj4[4];
  bool val4[4];
#pragma unroll
  for (int nt = 0; nt < 4; ++nt) {
    int jt = nt * 16 + r;
    val4[nt] = jt < 49;
    int jc = val4[nt] ? jt : 0;
    int yj = jc / 7, xj = jc - yj * 7;
    yj4[nt] = yj; xj4[nt] = xj;
    int hj = wbh + yj, wj = wbw + xj;
    rj4[nt] = (hj < 49 ? 0 : (hj < 53 ? 1 : 2)) * 3 + (wj < 49 ? 0 : (wj < 53 ? 1 : 2));
  }

  // ---- S = q @ k^T (K=32) ----
  f32x4 sA[4][4] = {};
  {
    bf16x8 qa[4];
#pragma unroll
    for (int mt = 0; mt < 4; ++mt) {
      int row = mt * 16 + r;
      qa[mt] = (row < 49) ? *(const bf16x8*)(base + row * 32 + g * 8) : zf;
    }
#pragma unroll
    for (int nt = 0; nt < 4; ++nt) {
      int rowk = nt * 16 + r;
      bf16x8 kf = (rowk < 49) ? *(const bf16x8*)(base + 1568 + rowk * 32 + g * 8) : zf;
#pragma unroll
      for (int mt = 0; mt < 4; ++mt)
        sA[mt][nt] = __builtin_amdgcn_mfma_f32_16x16x32_bf16(qa[mt], kf, sA[mt][nt], 0, 0, 0);
    }
  }
  // ---- softmax (+rpb +shift mask), write P (swizzled) ----
#pragma unroll
  for (int mt = 0; mt < 4; ++mt) {
#pragma unroll
    for (int j = 0; j < 4; ++j) {
      const int it = mt * 16 + g * 4 + j;
      if (it < 49) {
        int yi = it / 7, xi = it - yi * 7;
        int hi = wbh + yi, wi2 = wbw + xi;
        int ri = (hi < 49 ? 0 : (hi < 53 ? 1 : 2)) * 3 + (wi2 < 49 ? 0 : (wi2 < 53 ? 1 : 2));
        float v4[4];
#pragma unroll
        for (int nt = 0; nt < 4; ++nt) {
          float sv = -1e30f;
          if (val4[nt]) {
            sv = sA[mt][nt][j] + rpb[((yi - yj4[nt] + 6) * 13 + (xi - xj4[nt] + 6)) * 12 + head];
            if (ri != rj4[nt]) sv -= 100.f;
          }
          v4[nt] = sv;
        }
        float mx = fmaxf(fmaxf(v4[0], v4[1]), fmaxf(v4[2], v4[3]));
#pragma unroll
        for (int m = 1; m < 16; m <<= 1) mx = fmaxf(mx, __shfl_xor(mx, m, 64));
        float sum = 0.f;
#pragma unroll
        for (int nt = 0; nt < 4; ++nt) { v4[nt] = __expf(v4[nt] - mx); sum += v4[nt]; }
#pragma unroll
        for (int m = 1; m < 16; m <<= 1) sum += __shfl_xor(sum, m, 64);
        float inv = 1.f / sum;
#pragma unroll
        for (int nt = 0; nt < 4; ++nt) {
          int col = nt * 16 + r;
          int swz = ((col >> 3) ^ (it & 7));
          P_l[it * 64 + swz * 8 + (col & 7)] = __float2bfloat16(v4[nt] * inv);
        }
      }
    }
  }
  // ---- out = P @ V ----
  f32x4 oA[4][2] = {};
#pragma unroll
  for (int ks = 0; ks < 2; ++ks) {
    bf16x8 pa[4];
#pragma unroll
    for (int mt = 0; mt < 4; ++mt) {
      int row = mt * 16 + r;
      int swz = (ks * 4 + g) ^ (row & 7);
      pa[mt] = (row < 49) ? *(const bf16x8*)(&P_l[row * 64 + swz * 8]) : zf;
    }
#pragma unroll
    for (int nt = 0; nt < 2; ++nt) {
      bf16x8 vb = *(const bf16x8*)(base + 3136 + (nt * 16 + r) * 64 + ks * 32 + g * 8);
#pragma unroll
      for (int mt = 0; mt < 4; ++mt)
        oA[mt][nt] = __builtin_amdgcn_mfma_f32_16x16x32_bf16(pa[mt], vb, oA[mt][nt], 0, 0, 0);
    }
  }
#pragma unroll
  for (int mt = 0; mt < 4; ++mt)
#pragma unroll
    for (int nt = 0; nt < 2; ++nt)
#pragma unroll
      for (int j = 0; j < 4; ++j) {
        int row = mt * 16 + g * 4 + j;
        if (row < 49)
          ao[((size_t)win * 49 + row) * 384 + head * 32 + nt * 16 + r] =
              __float2bfloat16(oA[mt][nt][j]);
      }
}

// ---------- depthwise 3x3 (NHWC) + gelu*bn2 — register sliding window, 14 outputs/thread ----------
__global__ __launch_bounds__(256) void dw_kernel(const __hip_bfloat16* __restrict__ y1,
                                                 const float* __restrict__ wt,  // [9][384]
                                                 const float* __restrict__ wb,
                                                 const float* __restrict__ g2,
                                                 const float* __restrict__ b2,
                                                 __hip_bfloat16* __restrict__ y2) {
  const int tid = blockIdx.x * 256 + threadIdx.x;  // 32*56*4*48 = 344064
  const int c8 = tid % 48;
  int t = tid / 48;
  const int q = t & 3; t >>= 2;
  const int hq = t % 56;
  const int b = t / 56;
  const int cb = c8 * 8;
  const int x0 = q * 14;

  float wr[9][8];
#pragma unroll
  for (int k = 0; k < 9; ++k) {
    float4 a = *(const float4*)(wt + k * 384 + cb);
    float4 c = *(const float4*)(wt + k * 384 + cb + 4);
    wr[k][0] = a.x; wr[k][1] = a.y; wr[k][2] = a.z; wr[k][3] = a.w;
    wr[k][4] = c.x; wr[k][5] = c.y; wr[k][6] = c.z; wr[k][7] = c.w;
  }
  if (hq == 0) {
#pragma unroll
    for (int k = 0; k < 3; ++k)
#pragma unroll
      for (int i = 0; i < 8; ++i) wr[k][i] = 0.f;
  }
  if (hq == 55) {
#pragma unroll
    for (int k = 6; k < 9; ++k)
#pragma unroll
      for (int i = 0; i < 8; ++i) wr[k][i] = 0.f;
  }
  float bias[8], gv[8], bv[8];
  {
    float4 a = *(const float4*)(wb + cb), c = *(const float4*)(wb + cb + 4);
    bias[0] = a.x; bias[1] = a.y; bias[2] = a.z; bias[3] = a.w;
    bias[4] = c.x; bias[5] = c.y; bias[6] = c.z; bias[7] = c.w;
    float4 d = *(const float4*)(g2 + cb), e = *(const float4*)(g2 + cb + 4);
    gv[0] = d.x; gv[1] = d.y; gv[2] = d.z; gv[3] = d.w;
    gv[4] = e.x; gv[5] = e.y; gv[6] = e.z; gv[7] = e.w;
    float4 f = *(const float4*)(b2 + cb), h = *(const float4*)(b2 + cb + 4);
    bv[0] = f.x; bv[1] = f.y; bv[2] = f.z; bv[3] = f.w;
    bv[4] = h.x; bv[5] = h.y; bv[6] = h.z; bv[7] = h.w;
  }
  const int hm = hq > 0 ? hq - 1 : 0;
  const int hp = hq < 55 ? hq + 1 : 55;
  const __hip_bfloat16* r0 = y1 + ((size_t)(b * 3136 + hm * 56)) * 384 + cb;
  const __hip_bfloat16* r1 = y1 + ((size_t)(b * 3136 + hq * 56)) * 384 + cb;
  const __hip_bfloat16* r2 = y1 + ((size_t)(b * 3136 + hp * 56)) * 384 + cb;
  __hip_bfloat16* op = y2 + ((size_t)(b * 3136 + hq * 56)) * 384 + cb;

  u16x8 zv;
#pragma unroll
  for (int i = 0; i < 8; ++i) zv[i] = 0;
#define LDC(rp, x) (((unsigned)(x) < 56u) ? *(const u16x8*)((rp) + (size_t)(x) * 384) : zv)

  u16x8 L0 = LDC(r0, x0 - 1), L1 = LDC(r1, x0 - 1), L2 = LDC(r2, x0 - 1);
  u16x8 C0 = LDC(r0, x0), C1 = LDC(r1, x0), C2 = LDC(r2, x0);
#pragma unroll
  for (int xi = 0; xi < 14; ++xi) {
    const int x = x0 + xi;
    u16x8 R0 = LDC(r0, x + 1), R1 = LDC(r1, x + 1), R2 = LDC(r2, x + 1);
    float acc[8];
#pragma unroll
    for (int i = 0; i < 8; ++i) acc[i] = bias[i];
#pragma unroll
    for (int i = 0; i < 8; ++i) {
      acc[i] += __uint_as_float((unsigned)L0[i] << 16) * wr[0][i];
      acc[i] += __uint_as_float((unsigned)C0[i] << 16) * wr[1][i];
      acc[i] += __uint_as_float((unsigned)R0[i] << 16) * wr[2][i];
      acc[i] += __uint_as_float((unsigned)L1[i] << 16) * wr[3][i];
      acc[i] += __uint_as_float((unsigned)C1[i] << 16) * wr[4][i];
      acc[i] += __uint_as_float((unsigned)R1[i] << 16) * wr[5][i];
      acc[i] += __uint_as_float((unsigned)L2[i] << 16) * wr[6][i];
      acc[i] += __uint_as_float((unsigned)C2[i] << 16) * wr[7][i];
      acc[i] += __uint_as_float((unsigned)R2[i] << 16) * wr[8][i];
    }
    u16x8 o;
#pragma unroll
    for (int i = 0; i < 8; ++i) {
      float u = acc[i];
      float gl = 0.5f * u * (1.f + erff(u * 0.70710678118654752f));
      o[i] = f2u(gl * gv[i] + bv[i]);
    }
    *(u16x8*)(op + (size_t)x * 384) = o;
    L0 = C0; L1 = C1; L2 = C2;
    C0 = R0; C1 = R1; C2 = R2;
  }
#undef LDC
}

extern "C" void kernel_launch(void* const* d_in, const int* in_sizes, int n_in, void* d_out,
                              int out_size, void* d_ws, size_t ws_size, hipStream_t stream) {
  (void)in_sizes; (void)n_in; (void)out_size; (void)ws_size;
  const float* x = (const float*)d_in[0];
  const float* n1g = (const float*)d_in[1];
  const float* n1b = (const float*)d_in[2];
  const float* qkv_w = (const float*)d_in[3];
  const float* qkv_b = (const float*)d_in[4];
  const float* rpb = (const float*)d_in[5];
  const float* proj_w = (const float*)d_in[6];
  const float* proj_b = (const float*)d_in[7];
  const float* se1_w = (const float*)d_in[8];
  const float* se1_b = (const float*)d_in[9];
  const float* se2_w = (const float*)d_in[10];
  const float* se2_b = (const float*)d_in[11];
  const float* n2g = (const float*)d_in[12];
  const float* n2b = (const float*)d_in[13];
  const float* c1_w = (const float*)d_in[14];
  const float* c1_b = (const float*)d_in[15];
  const float* bn1g = (const float*)d_in[16];
  const float* bn1b = (const float*)d_in[17];
  const float* dw_w = (const float*)d_in[18];
  const float* dw_b = (const float*)d_in[19];
  const float* bn2g = (const float*)d_in[20];
  const float* bn2b = (const float*)d_in[21];
  const float* c2_w = (const float*)d_in[22];
  const float* c2_b = (const float*)d_in[23];
  const float* bn3g = (const float*)d_in[24];
  const float* bn3b = (const float*)d_in[25];

  char* ws = (char*)d_ws;
  __hip_bfloat16* r0b = (__hip_bfloat16*)ws;              // R0: xn / ao / ln2 / y2
  __hip_bfloat16* r1b = (__hip_bfloat16*)(ws + OFF_R1);   // R1: qkv chunks / g1 / y1
  __hip_bfloat16* wbp = (__hip_bfloat16*)(ws + OFF_WB);
  float* wt = (float*)(ws + OFF_WT);
  __hip_bfloat16* qkv_wb = wbp;             // 442368
  __hip_bfloat16* proj_wb = wbp + 442368;   // 147456
  __hip_bfloat16* se1_wb = wbp + 589824;    // 73728
  __hip_bfloat16* se2_wb = wbp + 663552;    // 73728
  __hip_bfloat16* c1_wb = wbp + 737280;     // 147456
  __hip_bfloat16* c2_wb = wbp + 884736;     // 147456
  float* out = (float*)d_out;

  cvt_kernel<<<1728, 256, 0, stream>>>(qkv_w, qkv_wb, 442368);
  cvt_kernel<<<576, 256, 0, stream>>>(proj_w, proj_wb, 147456);
  cvt_kernel<<<288, 256, 0, stream>>>(se1_w, se1_wb, 73728);
  cvt_kernel<<<288, 256, 0, stream>>>(se2_w, se2_wb, 73728);
  cvt_kernel<<<576, 256, 0, stream>>>(c1_w, c1_wb, 147456);
  cvt_kernel<<<576, 256, 0, stream>>>(c2_w, c2_wb, 147456);
  dwrep_kernel<<<14, 256, 0, stream>>>(dw_w, wt);

  // LN1 + shift + window partition -> xn (R0, bf16, windowed)
  ln_kernel<true><<<25088, 256, 0, stream>>>(x, n1g, n1b, r0b);

  // attention: 4 chunks of 512 windows; qkv GEMM -> R1, core -> ao over R0
  for (int c = 0; c < 4; ++c) {
    const __hip_bfloat16* xa = r0b + (size_t)c * 25088 * 384;
    gemm2<EPI_QKV, 384, false><<<dim3(196, 9), 256, 0, stream>>>(xa, qkv_wb, qkv_b, nullptr,
                                                                 nullptr, nullptr, r1b);
    attn_core<<<6144, 64, 0, stream>>>(r1b, rpb, r0b, c * 512);
  }

  // proj + window-reverse + roll-back + residual -> x1 (fp32, d_out)
  gemm2<EPI_PROJ, 384, false><<<dim3(784, 3), 256, 0, stream>>>(r0b, proj_wb, proj_b, x, nullptr,
                                                                nullptr, out);
  // SE: g1 = relu(x1 @ se1^T) -> R1 (bf16 [M][192])
  gemm2<EPI_SE1, 384, true><<<dim3(784, 2), 256, 0, stream>>>(out, se1_wb, se1_b, nullptr,
                                                              nullptr, nullptr, r1b);
  // x2 = x1 * sigmoid(g1 @ se2^T) -> d_out (in place)
  gemm2<EPI_SE2, 192, false><<<dim3(784, 3), 256, 0, stream>>>(r1b, se2_wb, se2_b, out, nullptr,
                                                               nullptr, out);
  // LN2 -> R0 (bf16, plain token order)
  ln_kernel<false><<<25088, 256, 0, stream>>>(out, n2g, n2b, r0b);
  // y1 = gelu(R0 @ c1^T)*bn1 -> R1
  gemm2<EPI_C1, 384, false><<<dim3(784, 3), 256, 0, stream>>>(r0b, c1_wb, c1_b, bn1g, bn1b,
                                                              nullptr, r1b);
  // y2 = gelu(dwconv(y1))*bn2 -> R0
  dw_kernel<<<1344, 256, 0, stream>>>(r1b, wt, dw_b, bn2g, bn2b, r0b);
  // out = x2 + (y2 @ c2^T)*bn3 -> d_out (in place)
  gemm2<EPI_C2, 384, false><<<dim3(784, 3), 256, 0, stream>>>(r0b, c2_wb, c2_b, bn3g, bn3b, out,
                                                              out);
}

// Round 6
// 1085.078 us; speedup vs baseline: 1.9687x; 1.0697x over previous
//
#include <hip/hip_runtime.h>
#include <hip/hip_bf16.h>

typedef __attribute__((ext_vector_type(4))) float f32x4;
typedef __attribute__((ext_vector_type(8))) __bf16 bf16x8;
typedef __attribute__((ext_vector_type(8))) unsigned short u16x8;

#define SCALE_ 0.17677669529663687f  /* 32^-0.5 */

// ---------- workspace layout (bytes) ----------
// R0 [0, 77070336): xn (windowed LN1 out) -> attn out (ao) -> ln2 out -> y2
// R1 [77070336, 154140672): qkv chunk buf (63.7MB) -> g1 (38.5MB) -> y1 (77MB)
#define OFF_R1 77070336ull
#define OFF_WB 154140672ull          // bf16 weight copies (1,032,192 elems)
#define OFF_WT 156205056ull          // f32 [9][384] repacked dw weights (13824 B)

__device__ __forceinline__ __bf16 tobf(float f) {
  __hip_bfloat16 h = __float2bfloat16(f);
  return __builtin_bit_cast(__bf16, h);
}
__device__ __forceinline__ unsigned short f2u(float f) {
  return __builtin_bit_cast(unsigned short, __float2bfloat16(f));
}

// ---------- fp32 -> bf16 weight copy ----------
__global__ __launch_bounds__(256) void cvt_kernel(const float* __restrict__ src,
                                                  __hip_bfloat16* __restrict__ dst, int n) {
  int i = blockIdx.x * 256 + threadIdx.x;
  int stride = gridDim.x * 256;
  for (; i < n; i += stride) dst[i] = __float2bfloat16(src[i]);
}

// ---------- repack dw weights [384][9] -> [9][384] ----------
__global__ __launch_bounds__(256) void dwrep_kernel(const float* __restrict__ src,
                                                    float* __restrict__ dst) {
  int i = blockIdx.x * 256 + threadIdx.x;
  if (i < 3456) {
    int c = i / 9, k = i - c * 9;
    dst[k * 384 + c] = src[i];
  }
}

// ---------- LayerNorm (one wave per token); WIN: write to rolled+windowed position ----------
template <bool WIN>
__global__ __launch_bounds__(256) void ln_kernel(const float* __restrict__ x,
                                                 const float* __restrict__ gm,
                                                 const float* __restrict__ bt,
                                                 __hip_bfloat16* __restrict__ out) {
  const int tok = blockIdx.x * 4 + (threadIdx.x >> 6);
  const int lane = threadIdx.x & 63;
  const float2* row = (const float2*)(x + (size_t)tok * 384);
  float2 v[3];
  v[0] = row[lane]; v[1] = row[lane + 64]; v[2] = row[lane + 128];
  float s = 0.f, sq = 0.f;
#pragma unroll
  for (int i = 0; i < 3; ++i) { s += v[i].x + v[i].y; sq += v[i].x * v[i].x + v[i].y * v[i].y; }
#pragma unroll
  for (int m = 1; m < 64; m <<= 1) { s += __shfl_xor(s, m, 64); sq += __shfl_xor(sq, m, 64); }
  const float mean = s * (1.f / 384.f);
  const float var = sq * (1.f / 384.f) - mean * mean;
  const float rstd = rsqrtf(var + 1e-5f);
  size_t dst;
  if constexpr (WIN) {
    int b = tok / 3136, l = tok - b * 3136;
    int i = l / 56, j = l - i * 56;
    int hp = i - 3; if (hp < 0) hp += 56;
    int wp = j - 3; if (wp < 0) wp += 56;
    int wi = (hp / 7) * 8 + wp / 7;
    int n = (hp % 7) * 7 + wp % 7;
    dst = (size_t)(b * 64 + wi) * 49 + n;
  } else {
    dst = (size_t)tok;
  }
  unsigned int* o = (unsigned int*)(out + dst * 384);
  const float2* G = (const float2*)gm;
  const float2* Bv = (const float2*)bt;
#pragma unroll
  for (int i = 0; i < 3; ++i) {
    int j = lane + 64 * i;
    float2 gv = G[j], bv = Bv[j];
    float a = (v[i].x - mean) * rstd * gv.x + bv.x;
    float b2 = (v[i].y - mean) * rstd * gv.y + bv.y;
    o[j] = (unsigned)f2u(a) | ((unsigned)f2u(b2) << 16);
  }
}

// ---------- A-read-once GEMM: block = 64 rows x NTOT cols, reg-prefetch pipeline ----------
enum { EPI_PROJ = 0, EPI_SE1 = 1, EPI_SE2 = 2, EPI_C1 = 3, EPI_C2 = 4, EPI_QKV = 5 };

template <int EPI, int KD, int NTOT, bool AF32>
__global__ __launch_bounds__(256) void gemm3(const void* __restrict__ Ap,
                                             const __hip_bfloat16* __restrict__ W,
                                             const float* __restrict__ bias,
                                             const float* __restrict__ p0,
                                             const float* __restrict__ p1,
                                             const float* __restrict__ p2,
                                             void* __restrict__ outp) {
  constexpr int NT = NTOT / 64;     // n-tiles (of 16) per wave: 384->6, 192->3
  constexpr int KS = KD / 32;       // K-steps
  const int tid = threadIdx.x;
  const int lane = tid & 63, wave = tid >> 6;
  const int g = lane >> 4, r = lane & 15;
  const int row0 = blockIdx.x * 64;
  const int n0 = wave * (NT * 16);
  const int sgrp = (EPI == EPI_QKV) ? blockIdx.y : 0;
  const __hip_bfloat16* Wb = W + (size_t)sgrp * 384 * KD;
  const float* biasb = bias + sgrp * 384;

  __shared__ __align__(16) __hip_bfloat16 Al[64][40];
  __shared__ __align__(16) __hip_bfloat16 Bl[NTOT][40];

  // staging coords: each thread owns A row (tid>>2), chunk (tid&3); B rows (tid>>2)+64h
  const int s_row = tid >> 2;
  const int s_c = (tid & 3) * 8;

  // A source row (gather through inverse window/roll map for PROJ)
  size_t arow;
  if constexpr (EPI == EPI_PROJ) {
    int t = row0 + s_row;
    int b = t / 3136, l = t - b * 3136;
    int i = l / 56, j = l - i * 56;
    int hp = i >= 3 ? i - 3 : i + 53;
    int wp = j >= 3 ? j - 3 : j + 53;
    arow = ((size_t)(b * 64 + (hp / 7) * 8 + wp / 7)) * 49 + (hp % 7) * 7 + (wp % 7);
  } else {
    arow = (size_t)(row0 + s_row);
  }

  f32x4 acc[4][NT] = {};

  // ---- prologue: load step-0 regs ----
  bf16x8 a_reg;
  bf16x8 b_reg[NT];
  {
    if constexpr (AF32) {
      const float* A = (const float*)Ap;
      const float4* sp = (const float4*)(A + arow * KD + s_c);
      float4 a = sp[0], b = sp[1];
      a_reg[0] = tobf(a.x); a_reg[1] = tobf(a.y); a_reg[2] = tobf(a.z); a_reg[3] = tobf(a.w);
      a_reg[4] = tobf(b.x); a_reg[5] = tobf(b.y); a_reg[6] = tobf(b.z); a_reg[7] = tobf(b.w);
    } else {
      a_reg = *(const bf16x8*)((const __hip_bfloat16*)Ap + arow * KD + s_c);
    }
#pragma unroll
    for (int h = 0; h < NT; ++h)
      b_reg[h] = *(const bf16x8*)(Wb + (size_t)(s_row + 64 * h) * KD + s_c);
  }

  for (int kk = 0; kk < KS; ++kk) {
    // commit step-kk regs to LDS
    *(bf16x8*)(&Al[s_row][s_c]) = a_reg;
#pragma unroll
    for (int h = 0; h < NT; ++h) *(bf16x8*)(&Bl[s_row + 64 * h][s_c]) = b_reg[h];
    __syncthreads();
    // issue step-kk+1 loads (latency hides under the MFMA phase below)
    if (kk + 1 < KS) {
      const int kb = (kk + 1) * 32 + s_c;
      if constexpr (AF32) {
        const float* A = (const float*)Ap;
        const float4* sp = (const float4*)(A + arow * KD + kb);
        float4 a = sp[0], b = sp[1];
        a_reg[0] = tobf(a.x); a_reg[1] = tobf(a.y); a_reg[2] = tobf(a.z); a_reg[3] = tobf(a.w);
        a_reg[4] = tobf(b.x); a_reg[5] = tobf(b.y); a_reg[6] = tobf(b.z); a_reg[7] = tobf(b.w);
      } else {
        a_reg = *(const bf16x8*)((const __hip_bfloat16*)Ap + arow * KD + kb);
      }
#pragma unroll
      for (int h = 0; h < NT; ++h)
        b_reg[h] = *(const bf16x8*)(Wb + (size_t)(s_row + 64 * h) * KD + kb);
    }
    // compute step kk
    bf16x8 af[4];
#pragma unroll
    for (int mt = 0; mt < 4; ++mt) af[mt] = *(const bf16x8*)(&Al[mt * 16 + r][g * 8]);
#pragma unroll
    for (int nt = 0; nt < NT; ++nt) {
      bf16x8 bf = *(const bf16x8*)(&Bl[n0 + nt * 16 + r][g * 8]);
#pragma unroll
      for (int mt = 0; mt < 4; ++mt)
        acc[mt][nt] = __builtin_amdgcn_mfma_f32_16x16x32_bf16(af[mt], bf, acc[mt][nt], 0, 0, 0);
    }
    __syncthreads();
  }

  // ---- epilogue ----
#pragma unroll
  for (int mt = 0; mt < 4; ++mt) {
#pragma unroll
    for (int j = 0; j < 4; ++j) {
      const int row = row0 + mt * 16 + g * 4 + j;
      size_t obase = 0;
      int win_l = 0, n = 0;
      if constexpr (EPI == EPI_QKV) {
        win_l = row / 49; n = row - win_l * 49;
      } else {
        obase = (size_t)row * (EPI == EPI_SE1 ? 192 : 384);
      }
#pragma unroll
      for (int nt = 0; nt < NT; ++nt) {
        const int col = n0 + nt * 16 + r;
        float v = acc[mt][nt][j] + biasb[col];
        if constexpr (EPI == EPI_PROJ) {
          ((float*)outp)[obase + col] = p0[obase + col] + v;  // + shortcut x (coalesced)
        } else if constexpr (EPI == EPI_SE1) {
          ((__hip_bfloat16*)outp)[obase + col] = __float2bfloat16(fmaxf(v, 0.f));
        } else if constexpr (EPI == EPI_SE2) {
          float gate = 1.f / (1.f + __expf(-v));
          ((float*)outp)[obase + col] = p0[obase + col] * gate;  // x2 = x1*sig (in-place ok)
        } else if constexpr (EPI == EPI_C1) {
          float gl = 0.5f * v * (1.f + erff(v * 0.70710678118654752f));
          ((__hip_bfloat16*)outp)[obase + col] = __float2bfloat16(gl * p0[col] + p1[col]);
        } else if constexpr (EPI == EPI_C2) {
          float y = v * p0[col] + p1[col];
          ((float*)outp)[obase + col] = p2[obase + col] + y;  // final = x2 + y (in-place ok)
        } else {  // EPI_QKV: q[49][32] | k[49][32] | vT[32][64] per (win,head)
          const int head = col >> 5, d = col & 31;
          __hip_bfloat16* qk = (__hip_bfloat16*)outp;
          const size_t hb = (size_t)win_l * 62208 + (size_t)head * 5184;
          if (sgrp == 0) qk[hb + n * 32 + d] = __float2bfloat16(v * SCALE_);
          else if (sgrp == 1) qk[hb + 1568 + n * 32 + d] = __float2bfloat16(v);
          else qk[hb + 3136 + d * 64 + n] = __float2bfloat16(v);
        }
      }
    }
  }
}

// ---------- attention core: one 64-thread block per (window, head) ----------
__global__ __launch_bounds__(64) void attn_core(const __hip_bfloat16* __restrict__ qkv,
                                                const float* __restrict__ rpb,
                                                __hip_bfloat16* __restrict__ ao, int win0) {
  const int bid = blockIdx.x;
  const int win_l = bid / 12, head = bid - win_l * 12;
  const int win = win0 + win_l;
  const int widx = win & 63;
  const int lane = threadIdx.x;
  const int g = lane >> 4, r = lane & 15;
  const int wbh = (widx >> 3) * 7, wbw = (widx & 7) * 7;
  const __hip_bfloat16* base = qkv + (size_t)win_l * 62208 + (size_t)head * 5184;

  // P [49][64] bf16, 16B chunks XOR-swizzled by (row&7)
  __shared__ __align__(16) __hip_bfloat16 P_l[49 * 64];

  bf16x8 zf;
#pragma unroll
  for (int i = 0; i < 8; ++i) zf[i] = tobf(0.f);

  // column geometry (depends only on r)
  int yj4[4], xj4[4], rj4[4];
  bool val4[4];
#pragma unroll
  for (int nt = 0; nt < 4; ++nt) {
    int jt = nt * 16 + r;
    val4[nt] = jt < 49;
    int jc = val4[nt] ? jt : 0;
    int yj = jc / 7, xj = jc - yj * 7;
    yj4[nt] = yj; xj4[nt] = xj;
    int hj = wbh + yj, wj = wbw + xj;
    rj4[nt] = (hj < 49 ? 0 : (hj < 53 ? 1 : 2)) * 3 + (wj < 49 ? 0 : (wj < 53 ? 1 : 2));
  }

  // ---- S = q @ k^T (K=32) ----
  f32x4 sA[4][4] = {};
  {
    bf16x8 qa[4];
#pragma unroll
    for (int mt = 0; mt < 4; ++mt) {
      int row = mt * 16 + r;
      qa[mt] = (row < 49) ? *(const bf16x8*)(base + row * 32 + g * 8) : zf;
    }
#pragma unroll
    for (int nt = 0; nt < 4; ++nt) {
      int rowk = nt * 16 + r;
      bf16x8 kf = (rowk < 49) ? *(const bf16x8*)(base + 1568 + rowk * 32 + g * 8) : zf;
#pragma unroll
      for (int mt = 0; mt < 4; ++mt)
        sA[mt][nt] = __builtin_amdgcn_mfma_f32_16x16x32_bf16(qa[mt], kf, sA[mt][nt], 0, 0, 0);
    }
  }
  // ---- softmax (+rpb +shift mask), write P (swizzled) ----
#pragma unroll
  for (int mt = 0; mt < 4; ++mt) {
#pragma unroll
    for (int j = 0; j < 4; ++j) {
      const int it = mt * 16 + g * 4 + j;
      if (it < 49) {
        int yi = it / 7, xi = it - yi * 7;
        int hi = wbh + yi, wi2 = wbw + xi;
        int ri = (hi < 49 ? 0 : (hi < 53 ? 1 : 2)) * 3 + (wi2 < 49 ? 0 : (wi2 < 53 ? 1 : 2));
        float v4[4];
#pragma unroll
        for (int nt = 0; nt < 4; ++nt) {
          float sv = -1e30f;
          if (val4[nt]) {
            sv = sA[mt][nt][j] + rpb[((yi - yj4[nt] + 6) * 13 + (xi - xj4[nt] + 6)) * 12 + head];
            if (ri != rj4[nt]) sv -= 100.f;
          }
          v4[nt] = sv;
        }
        float mx = fmaxf(fmaxf(v4[0], v4[1]), fmaxf(v4[2], v4[3]));
#pragma unroll
        for (int m = 1; m < 16; m <<= 1) mx = fmaxf(mx, __shfl_xor(mx, m, 64));
        float sum = 0.f;
#pragma unroll
        for (int nt = 0; nt < 4; ++nt) { v4[nt] = __expf(v4[nt] - mx); sum += v4[nt]; }
#pragma unroll
        for (int m = 1; m < 16; m <<= 1) sum += __shfl_xor(sum, m, 64);
        float inv = 1.f / sum;
#pragma unroll
        for (int nt = 0; nt < 4; ++nt) {
          int col = nt * 16 + r;
          int swz = ((col >> 3) ^ (it & 7));
          P_l[it * 64 + swz * 8 + (col & 7)] = __float2bfloat16(v4[nt] * inv);
        }
      }
    }
  }
  // ---- out = P @ V ----
  f32x4 oA[4][2] = {};
#pragma unroll
  for (int ks = 0; ks < 2; ++ks) {
    bf16x8 pa[4];
#pragma unroll
    for (int mt = 0; mt < 4; ++mt) {
      int row = mt * 16 + r;
      int swz = (ks * 4 + g) ^ (row & 7);
      pa[mt] = (row < 49) ? *(const bf16x8*)(&P_l[row * 64 + swz * 8]) : zf;
    }
#pragma unroll
    for (int nt = 0; nt < 2; ++nt) {
      bf16x8 vb = *(const bf16x8*)(base + 3136 + (nt * 16 + r) * 64 + ks * 32 + g * 8);
#pragma unroll
      for (int mt = 0; mt < 4; ++mt)
        oA[mt][nt] = __builtin_amdgcn_mfma_f32_16x16x32_bf16(pa[mt], vb, oA[mt][nt], 0, 0, 0);
    }
  }
#pragma unroll
  for (int mt = 0; mt < 4; ++mt)
#pragma unroll
    for (int nt = 0; nt < 2; ++nt)
#pragma unroll
      for (int j = 0; j < 4; ++j) {
        int row = mt * 16 + g * 4 + j;
        if (row < 49)
          ao[((size_t)win * 49 + row) * 384 + head * 32 + nt * 16 + r] =
              __float2bfloat16(oA[mt][nt][j]);
      }
}

// ---------- depthwise 3x3 (NHWC) + gelu*bn2 — register sliding window, 14 outputs/thread ----------
__global__ __launch_bounds__(256) void dw_kernel(const __hip_bfloat16* __restrict__ y1,
                                                 const float* __restrict__ wt,  // [9][384]
                                                 const float* __restrict__ wb,
                                                 const float* __restrict__ g2,
                                                 const float* __restrict__ b2,
                                                 __hip_bfloat16* __restrict__ y2) {
  const int tid = blockIdx.x * 256 + threadIdx.x;  // 32*56*4*48 = 344064
  const int c8 = tid % 48;
  int t = tid / 48;
  const int q = t & 3; t >>= 2;
  const int hq = t % 56;
  const int b = t / 56;
  const int cb = c8 * 8;
  const int x0 = q * 14;

  float wr[9][8];
#pragma unroll
  for (int k = 0; k < 9; ++k) {
    float4 a = *(const float4*)(wt + k * 384 + cb);
    float4 c = *(const float4*)(wt + k * 384 + cb + 4);
    wr[k][0] = a.x; wr[k][1] = a.y; wr[k][2] = a.z; wr[k][3] = a.w;
    wr[k][4] = c.x; wr[k][5] = c.y; wr[k][6] = c.z; wr[k][7] = c.w;
  }
  if (hq == 0) {
#pragma unroll
    for (int k = 0; k < 3; ++k)
#pragma unroll
      for (int i = 0; i < 8; ++i) wr[k][i] = 0.f;
  }
  if (hq == 55) {
#pragma unroll
    for (int k = 6; k < 9; ++k)
#pragma unroll
      for (int i = 0; i < 8; ++i) wr[k][i] = 0.f;
  }
  float bias[8], gv[8], bv[8];
  {
    float4 a = *(const float4*)(wb + cb), c = *(const float4*)(wb + cb + 4);
    bias[0] = a.x; bias[1] = a.y; bias[2] = a.z; bias[3] = a.w;
    bias[4] = c.x; bias[5] = c.y; bias[6] = c.z; bias[7] = c.w;
    float4 d = *(const float4*)(g2 + cb), e = *(const float4*)(g2 + cb + 4);
    gv[0] = d.x; gv[1] = d.y; gv[2] = d.z; gv[3] = d.w;
    gv[4] = e.x; gv[5] = e.y; gv[6] = e.z; gv[7] = e.w;
    float4 f = *(const float4*)(b2 + cb), h = *(const float4*)(b2 + cb + 4);
    bv[0] = f.x; bv[1] = f.y; bv[2] = f.z; bv[3] = f.w;
    bv[4] = h.x; bv[5] = h.y; bv[6] = h.z; bv[7] = h.w;
  }
  const int hm = hq > 0 ? hq - 1 : 0;
  const int hp = hq < 55 ? hq + 1 : 55;
  const __hip_bfloat16* r0 = y1 + ((size_t)(b * 3136 + hm * 56)) * 384 + cb;
  const __hip_bfloat16* r1 = y1 + ((size_t)(b * 3136 + hq * 56)) * 384 + cb;
  const __hip_bfloat16* r2 = y1 + ((size_t)(b * 3136 + hp * 56)) * 384 + cb;
  __hip_bfloat16* op = y2 + ((size_t)(b * 3136 + hq * 56)) * 384 + cb;

  u16x8 zv;
#pragma unroll
  for (int i = 0; i < 8; ++i) zv[i] = 0;
#define LDC(rp, x) (((unsigned)(x) < 56u) ? *(const u16x8*)((rp) + (size_t)(x) * 384) : zv)

  u16x8 L0 = LDC(r0, x0 - 1), L1 = LDC(r1, x0 - 1), L2 = LDC(r2, x0 - 1);
  u16x8 C0 = LDC(r0, x0), C1 = LDC(r1, x0), C2 = LDC(r2, x0);
#pragma unroll
  for (int xi = 0; xi < 14; ++xi) {
    const int x = x0 + xi;
    u16x8 R0 = LDC(r0, x + 1), R1 = LDC(r1, x + 1), R2 = LDC(r2, x + 1);
    float acc[8];
#pragma unroll
    for (int i = 0; i < 8; ++i) acc[i] = bias[i];
#pragma unroll
    for (int i = 0; i < 8; ++i) {
      acc[i] += __uint_as_float((unsigned)L0[i] << 16) * wr[0][i];
      acc[i] += __uint_as_float((unsigned)C0[i] << 16) * wr[1][i];
      acc[i] += __uint_as_float((unsigned)R0[i] << 16) * wr[2][i];
      acc[i] += __uint_as_float((unsigned)L1[i] << 16) * wr[3][i];
      acc[i] += __uint_as_float((unsigned)C1[i] << 16) * wr[4][i];
      acc[i] += __uint_as_float((unsigned)R1[i] << 16) * wr[5][i];
      acc[i] += __uint_as_float((unsigned)L2[i] << 16) * wr[6][i];
      acc[i] += __uint_as_float((unsigned)C2[i] << 16) * wr[7][i];
      acc[i] += __uint_as_float((unsigned)R2[i] << 16) * wr[8][i];
    }
    u16x8 o;
#pragma unroll
    for (int i = 0; i < 8; ++i) {
      float u = acc[i];
      float gl = 0.5f * u * (1.f + erff(u * 0.70710678118654752f));
      o[i] = f2u(gl * gv[i] + bv[i]);
    }
    *(u16x8*)(op + (size_t)x * 384) = o;
    L0 = C0; L1 = C1; L2 = C2;
    C0 = R0; C1 = R1; C2 = R2;
  }
#undef LDC
}

extern "C" void kernel_launch(void* const* d_in, const int* in_sizes, int n_in, void* d_out,
                              int out_size, void* d_ws, size_t ws_size, hipStream_t stream) {
  (void)in_sizes; (void)n_in; (void)out_size; (void)ws_size;
  const float* x = (const float*)d_in[0];
  const float* n1g = (const float*)d_in[1];
  const float* n1b = (const float*)d_in[2];
  const float* qkv_w = (const float*)d_in[3];
  const float* qkv_b = (const float*)d_in[4];
  const float* rpb = (const float*)d_in[5];
  const float* proj_w = (const float*)d_in[6];
  const float* proj_b = (const float*)d_in[7];
  const float* se1_w = (const float*)d_in[8];
  const float* se1_b = (const float*)d_in[9];
  const float* se2_w = (const float*)d_in[10];
  const float* se2_b = (const float*)d_in[11];
  const float* n2g = (const float*)d_in[12];
  const float* n2b = (const float*)d_in[13];
  const float* c1_w = (const float*)d_in[14];
  const float* c1_b = (const float*)d_in[15];
  const float* bn1g = (const float*)d_in[16];
  const float* bn1b = (const float*)d_in[17];
  const float* dw_w = (const float*)d_in[18];
  const float* dw_b = (const float*)d_in[19];
  const float* bn2g = (const float*)d_in[20];
  const float* bn2b = (const float*)d_in[21];
  const float* c2_w = (const float*)d_in[22];
  const float* c2_b = (const float*)d_in[23];
  const float* bn3g = (const float*)d_in[24];
  const float* bn3b = (const float*)d_in[25];

  char* ws = (char*)d_ws;
  __hip_bfloat16* r0b = (__hip_bfloat16*)ws;              // R0: xn / ao / ln2 / y2
  __hip_bfloat16* r1b = (__hip_bfloat16*)(ws + OFF_R1);   // R1: qkv chunks / g1 / y1
  __hip_bfloat16* wbp = (__hip_bfloat16*)(ws + OFF_WB);
  float* wt = (float*)(ws + OFF_WT);
  __hip_bfloat16* qkv_wb = wbp;             // 442368
  __hip_bfloat16* proj_wb = wbp + 442368;   // 147456
  __hip_bfloat16* se1_wb = wbp + 589824;    // 73728
  __hip_bfloat16* se2_wb = wbp + 663552;    // 73728
  __hip_bfloat16* c1_wb = wbp + 737280;     // 147456
  __hip_bfloat16* c2_wb = wbp + 884736;     // 147456
  float* out = (float*)d_out;

  cvt_kernel<<<1728, 256, 0, stream>>>(qkv_w, qkv_wb, 442368);
  cvt_kernel<<<576, 256, 0, stream>>>(proj_w, proj_wb, 147456);
  cvt_kernel<<<288, 256, 0, stream>>>(se1_w, se1_wb, 73728);
  cvt_kernel<<<288, 256, 0, stream>>>(se2_w, se2_wb, 73728);
  cvt_kernel<<<576, 256, 0, stream>>>(c1_w, c1_wb, 147456);
  cvt_kernel<<<576, 256, 0, stream>>>(c2_w, c2_wb, 147456);
  dwrep_kernel<<<14, 256, 0, stream>>>(dw_w, wt);

  // LN1 + shift + window partition -> xn (R0, bf16, windowed)
  ln_kernel<true><<<25088, 256, 0, stream>>>(x, n1g, n1b, r0b);

  // attention: 4 chunks of 512 windows; qkv GEMM (grid.y = s) -> R1, core -> ao over R0
  for (int c = 0; c < 4; ++c) {
    const __hip_bfloat16* xa = r0b + (size_t)c * 25088 * 384;
    gemm3<EPI_QKV, 384, 384, false><<<dim3(392, 3), 256, 0, stream>>>(
        xa, qkv_wb, qkv_b, nullptr, nullptr, nullptr, r1b);
    attn_core<<<6144, 64, 0, stream>>>(r1b, rpb, r0b, c * 512);
  }

  // proj (image-order out, A gathered) + residual -> x1 (fp32, d_out)
  gemm3<EPI_PROJ, 384, 384, false><<<1568, 256, 0, stream>>>(r0b, proj_wb, proj_b, x, nullptr,
                                                             nullptr, out);
  // SE: g1 = relu(x1 @ se1^T) -> R1 (bf16 [M][192])
  gemm3<EPI_SE1, 384, 192, true><<<1568, 256, 0, stream>>>(out, se1_wb, se1_b, nullptr, nullptr,
                                                           nullptr, r1b);
  // x2 = x1 * sigmoid(g1 @ se2^T) -> d_out (in place)
  gemm3<EPI_SE2, 192, 384, false><<<1568, 256, 0, stream>>>(r1b, se2_wb, se2_b, out, nullptr,
                                                            nullptr, out);
  // LN2 -> R0 (bf16, plain token order)
  ln_kernel<false><<<25088, 256, 0, stream>>>(out, n2g, n2b, r0b);
  // y1 = gelu(R0 @ c1^T)*bn1 -> R1
  gemm3<EPI_C1, 384, 384, false><<<1568, 256, 0, stream>>>(r0b, c1_wb, c1_b, bn1g, bn1b, nullptr,
                                                           r1b);
  // y2 = gelu(dwconv(y1))*bn2 -> R0
  dw_kernel<<<1344, 256, 0, stream>>>(r1b, wt, dw_b, bn2g, bn2b, r0b);
  // out = x2 + (y2 @ c2^T)*bn3 -> d_out (in place)
  gemm3<EPI_C2, 384, 384, false><<<1568, 256, 0, stream>>>(r0b, c2_wb, c2_b, bn3g, bn3b, out,
                                                           out);
}